// Round 9
// baseline (164.729 us; speedup 1.0000x reference)
//
#include <hip/hip_runtime.h>
#include <hip/hip_bf16.h>
#include <math.h>

#define S_ 2048

typedef __attribute__((ext_vector_type(8))) short bf16x8;
typedef __attribute__((ext_vector_type(4))) float f32x4;
typedef __attribute__((ext_vector_type(16))) float f32x16;
typedef __attribute__((ext_vector_type(8))) unsigned short u16x8;
typedef __attribute__((ext_vector_type(4))) unsigned short u16x4;

__device__ inline unsigned short f2bf(float f) {
  union { float f; unsigned u; } x; x.f = f;
  unsigned r = x.u + 0x7fff + ((x.u >> 16) & 1);
  return (unsigned short)(r >> 16);
}

__device__ __forceinline__ void gll16(const unsigned short* g, unsigned short* l) {
  __builtin_amdgcn_global_load_lds(
      (const __attribute__((address_space(1))) unsigned int*)g,
      (__attribute__((address_space(3))) unsigned int*)l, 16, 0, 0);
}

// ---------------- bias table: bias[h][rel + 2047], rel = k - q ----------------
__global__ void bias_table_kernel(const float* __restrict__ table,
                                  float* __restrict__ biasTab) {
  int idx = blockIdx.x * blockDim.x + threadIdx.x;
  if (idx >= 16 * 4096) return;
  int h = idx >> 12;
  int r = idx & 4095;
  int rel = r - 2047;                  // mem - ctx
  int bucket = rel > 0 ? 16 : 0;
  int ar = rel < 0 ? -rel : rel;
  if (ar < 8) {
    bucket += ar;
  } else {
    float tmp = logf((float)ar / 8.0f);
    float lf = tmp / 2.7725887222397811f * 8.0f;
    int large = 8 + (int)lf;
    bucket += (large < 15 ? large : 15);
  }
  biasTab[idx] = table[h * 32 + bucket];
}

// ---------------- fp32 -> bf16 elementwise (8 per thread) ----------------
__global__ __launch_bounds__(256) void cvt_bf16_kernel(
    const float* __restrict__ in, unsigned short* __restrict__ out, int n8) {
  int i = blockIdx.x * blockDim.x + threadIdx.x;
  if (i >= n8) return;
  float4 a = ((const float4*)in)[i * 2];
  float4 b = ((const float4*)in)[i * 2 + 1];
  u16x8 o;
  o[0] = f2bf(a.x); o[1] = f2bf(a.y); o[2] = f2bf(a.z); o[3] = f2bf(a.w);
  o[4] = f2bf(b.x); o[5] = f2bf(b.y); o[6] = f2bf(b.z); o[7] = f2bf(b.w);
  *(u16x8*)&out[(size_t)i * 8] = o;
}

// ---------------- fp32 [K][N] -> bf16 [N][K] transpose ----------------
__global__ __launch_bounds__(256) void transpose_cvt_kernel(
    const float* __restrict__ in, unsigned short* __restrict__ out,
    int K, int N) {
  __shared__ unsigned short tile[64][72];
  const int k0 = blockIdx.y * 64, n0 = blockIdx.x * 64;
  const int tid = threadIdx.x;
  const int rr = tid >> 4, cc = (tid & 15) * 4;
#pragma unroll
  for (int p = 0; p < 4; ++p) {
    int k = rr + p * 16;
    float4 v = *(const float4*)&in[(size_t)(k0 + k) * N + n0 + cc];
    tile[k][cc + 0] = f2bf(v.x);
    tile[k][cc + 1] = f2bf(v.y);
    tile[k][cc + 2] = f2bf(v.z);
    tile[k][cc + 3] = f2bf(v.w);
  }
  __syncthreads();
#pragma unroll
  for (int p = 0; p < 4; ++p) {
    int n = rr + p * 16;
    u16x4 o;
    o[0] = tile[cc + 0][n];
    o[1] = tile[cc + 1][n];
    o[2] = tile[cc + 2][n];
    o[3] = tile[cc + 3][n];
    *(u16x4*)&out[(size_t)(n0 + n) * K + k0 + cc] = o;
  }
}

// ---------------- bf16 MFMA GEMM: C[M][N] = A[M][K] @ Bt[N][K]^T + bias ------
template <bool BF16OUT>
__global__ __launch_bounds__(256) void gemm_mfma_kernel(
    const unsigned short* __restrict__ A, const unsigned short* __restrict__ Bt,
    const float* __restrict__ bias, void* __restrict__ Cout,
    int M, int N, int K) {
  __shared__ __align__(16) unsigned short As[128 * 32];
  __shared__ __align__(16) unsigned short Bs[128 * 32];
  const int tid = threadIdx.x;
  const int wave = tid >> 6, lane = tid & 63;
  const int lg = lane >> 4, lr = lane & 15;
  const int m0 = blockIdx.y * 128, n0 = blockIdx.x * 128;
  const int wm = (wave & 1) * 64, wn = (wave >> 1) * 64;

  f32x4 acc[4][4] = {};

  const int r0 = tid >> 2;
  const int sw = ((tid & 3) ^ (r0 & 3)) << 3;
  const unsigned short* aP0 = A + (size_t)(m0 + r0) * K + sw;
  const unsigned short* aP1 = A + (size_t)(m0 + 64 + r0) * K + sw;
  const unsigned short* bP0 = Bt + (size_t)(n0 + r0) * K + sw;
  const unsigned short* bP1 = Bt + (size_t)(n0 + 64 + r0) * K + sw;
  unsigned short* ldsA0 = &As[(tid & ~63) * 8];
  unsigned short* ldsA1 = &As[(256 + (tid & ~63)) * 8];
  unsigned short* ldsB0 = &Bs[(tid & ~63) * 8];
  unsigned short* ldsB1 = &Bs[(256 + (tid & ~63)) * 8];

  const int swz = (lg ^ (lr & 3)) << 3;

  for (int kt = 0; kt < K; kt += 32) {
    __syncthreads();
    gll16(aP0 + kt, ldsA0);
    gll16(aP1 + kt, ldsA1);
    gll16(bP0 + kt, ldsB0);
    gll16(bP1 + kt, ldsB1);
    __syncthreads();
    bf16x8 af[4], bfr[4];
#pragma unroll
    for (int t = 0; t < 4; ++t) {
      af[t]  = *(const bf16x8*)&As[(wm + t * 16 + lr) * 32 + swz];
      bfr[t] = *(const bf16x8*)&Bs[(wn + t * 16 + lr) * 32 + swz];
    }
#pragma unroll
    for (int i = 0; i < 4; ++i)
#pragma unroll
      for (int j = 0; j < 4; ++j)
        acc[i][j] = __builtin_amdgcn_mfma_f32_16x16x32_bf16(
            af[i], bfr[j], acc[i][j], 0, 0, 0);
  }

  float bv[4];
#pragma unroll
  for (int j = 0; j < 4; ++j) bv[j] = bias[n0 + wn + j * 16 + lr];
#pragma unroll
  for (int i = 0; i < 4; ++i) {
#pragma unroll
    for (int j = 0; j < 4; ++j) {
#pragma unroll
      for (int r = 0; r < 4; ++r) {
        int row = m0 + wm + i * 16 + lg * 4 + r;
        int col = n0 + wn + j * 16 + lr;
        float val = acc[i][j][r] + bv[j];
        if constexpr (BF16OUT)
          ((unsigned short*)Cout)[(size_t)row * N + col] = f2bf(val);
        else
          ((float*)Cout)[(size_t)row * N + col] = val;
      }
    }
  }
}

// ---------------- V permute pre-pass (32x32 kappa order) ----------------
// vP[bb][h][d][pos]: per 64-k tile t, 16B slot ps = (2c+hi) ^ (d&7) holds
// elems e with k_within = 16c + (e&3) + 8*(e>>2) + 4*hi.
__global__ __launch_bounds__(256) void vperm_kernel(
    const unsigned short* __restrict__ qkvb, unsigned short* __restrict__ vP) {
  const int t = blockIdx.x, h = blockIdx.y, bb = blockIdx.z;
  __shared__ unsigned short tile[64][72];
  const int tid = threadIdx.x;
  {
    int k = tid >> 2, c = (tid & 3) * 16;
    const unsigned short* src =
        qkvb + (size_t)(bb * S_ + t * 64 + k) * 3072 + 2048 + h * 64 + c;
    *(bf16x8*)&tile[k][c] = *(const bf16x8*)src;
    *(bf16x8*)&tile[k][c + 8] = *(const bf16x8*)(src + 8);
  }
  __syncthreads();
  const int d = tid >> 2, m0 = (tid & 3) * 16;
  unsigned short* dst =
      vP + ((size_t)((bb * 16 + h) * 64 + d)) * S_ + t * 64 + m0;
#pragma unroll
  for (int half = 0; half < 2; ++half) {
    u16x8 o;
#pragma unroll
    for (int j = 0; j < 8; ++j) {
      int m = m0 + half * 8 + j;
      int ps = m >> 3, e = m & 7;
      int ls = ps ^ (d & 7);
      int c = ls >> 1, hi2 = ls & 1;
      int kw = 16 * c + (e & 3) + 8 * (e >> 2) + 4 * hi2;
      o[j] = tile[kw][d];
    }
    *(u16x8*)(dst + half * 8) = o;
  }
}

// ---------------- bf16 MFMA flash attention v5' (32x32x16, de-risked) --------
// 4 waves x 32 q-rows (q-tile 128), K-tile 64. 256 threads, grid 512.
// Swapped QK^T (S^T: col=q=lane&31), in-lane softmax, P as PV B-operand.
__global__ __launch_bounds__(256) void attn_mfma5_kernel(
    const unsigned short* __restrict__ qkvb, const unsigned short* __restrict__ vP,
    const float* __restrict__ biasTab, unsigned short* __restrict__ ctxb) {
  // bijective XCD swizzle: 512 wgs, 64 per XCD
  const int wg0 = blockIdx.x;
  const int wg = (wg0 & 7) * 64 + (wg0 >> 3);
  const int qt = wg & 15;
  const int h  = (wg >> 4) & 15;
  const int bb = wg >> 8;

  const int tid = threadIdx.x;
  const int wave = tid >> 6;     // 0..3
  const int lane = tid & 63;
  const int l5 = lane & 31;
  const int hi = lane >> 5;

  __shared__ __align__(16) unsigned short Klds[2][4096];  // [64 k][8 slot][8]
  __shared__ __align__(16) unsigned short Vlds[2][4096];  // [64 d][8 slot][8]
  __shared__ float biasW[2][192];

  const int q0 = qt * 128;
  const int qg = q0 + wave * 32 + l5;    // this lane's q row (S^T column)

  // Q B-frags: qf[c] = Q[qg][c*16 + hi*8 .. +7]
  bf16x8 qf[4];
#pragma unroll
  for (int c = 0; c < 4; ++c)
    qf[c] = *(const bf16x8*)(qkvb +
        (size_t)(bb * S_ + qg) * 3072 + h * 64 + c * 16 + hi * 8);

  float mrun = -1e30f;
  float lrun = 0.f;
  f32x16 ov0 = {}, ov1 = {};

  // ---- staging: 512 chunks of 16B per tile, 2 per thread ----
  const int kk = tid >> 3, kps = tid & 7;
  const unsigned short* kptr0 = qkvb + (size_t)(bb * S_ + kk) * 3072 + 1024 +
                                h * 64 + ((kps ^ (kk & 7)) * 8);
  const unsigned short* kptr1 = qkvb + (size_t)(bb * S_ + 32 + kk) * 3072 + 1024 +
                                h * 64 + ((kps ^ (kk & 7)) * 8);
  const unsigned short* vPbase = vP + ((size_t)((bb * 16 + h) * 64)) * S_;
  const unsigned short* vptr0 = vPbase + (size_t)kk * S_ + kps * 8;
  const unsigned short* vptr1 = vPbase + (size_t)(32 + kk) * S_ + kps * 8;
  const float* btabH = biasTab + h * 4096 + 2047;

  auto nonuni = [&](int tt) {
    int rl = tt * 64 - q0;
    return !((rl - 127 >= 91) || (rl + 63 <= -91));
  };

  // ---- prologue: stage tile 0 ----
  gll16(kptr0, &Klds[0][(tid & ~63) * 8]);
  gll16(kptr1, &Klds[0][2048 + (tid & ~63) * 8]);
  gll16(vptr0, &Vlds[0][(tid & ~63) * 8]);
  gll16(vptr1, &Vlds[0][2048 + (tid & ~63) * 8]);
  if (nonuni(0) && tid < 192) biasW[0][tid] = btabH[-q0 - 127 + tid];

  for (int t = 0; t < 32; ++t) {
    const int cur = t & 1;
    __syncthreads();   // drains gll16 (vmcnt) + bias writes; swaps buffers

    if (t < 31) {
      const size_t kadv = (size_t)(t + 1) * 64 * 3072;
      gll16(kptr0 + kadv, &Klds[cur ^ 1][(tid & ~63) * 8]);
      gll16(kptr1 + kadv, &Klds[cur ^ 1][2048 + (tid & ~63) * 8]);
      gll16(vptr0 + (t + 1) * 64, &Vlds[cur ^ 1][(tid & ~63) * 8]);
      gll16(vptr1 + (t + 1) * 64, &Vlds[cur ^ 1][2048 + (tid & ~63) * 8]);
      if (nonuni(t + 1) && tid < 192)
        biasW[cur ^ 1][tid] = btabH[(t + 1) * 64 - q0 - 127 + tid];
    }

    // ---- QK^T swapped: S^T rows = k, cols = q = l5 ----
    f32x16 sc0 = {}, sc1 = {};
#pragma unroll
    for (int c = 0; c < 4; ++c) {
      const int slot = ((2 * c + hi) ^ (l5 & 7)) * 8;
      bf16x8 kf0 = *(const bf16x8*)&Klds[cur][l5 * 64 + slot];
      bf16x8 kf1 = *(const bf16x8*)&Klds[cur][(32 + l5) * 64 + slot];
      sc0 = __builtin_amdgcn_mfma_f32_32x32x16_bf16(kf0, qf[c], sc0, 0, 0, 0);
      sc1 = __builtin_amdgcn_mfma_f32_32x32x16_bf16(kf1, qf[c], sc1, 0, 0, 0);
    }

    // ---- bias: sc_s[r] = S^T[64t + 32s + (r&3)+8(r>>2)+4hi][qg] ----
    float p0[16], p1[16];
    if (nonuni(t)) {
      const int jb = 127 - wave * 32 - l5 + 4 * hi;
#pragma unroll
      for (int r = 0; r < 16; ++r) {
        const int off = (r & 3) + 8 * (r >> 2);
        p0[r] = sc0[r] * 0.125f + biasW[cur][jb + off];
        p1[r] = sc1[r] * 0.125f + biasW[cur][jb + 32 + off];
      }
    } else {
      const float cb = btabH[t * 64 - q0];
#pragma unroll
      for (int r = 0; r < 16; ++r) {
        p0[r] = sc0[r] * 0.125f + cb;
        p1[r] = sc1[r] * 0.125f + cb;
      }
    }

    // ---- row max: in-lane tree over 32 + 1 shuffle ----
    float mx[16];
#pragma unroll
    for (int r = 0; r < 16; ++r) mx[r] = fmaxf(p0[r], p1[r]);
#pragma unroll
    for (int s = 8; s > 0; s >>= 1)
#pragma unroll
      for (int r = 0; r < s; ++r) mx[r] = fmaxf(mx[r], mx[r + s]);
    float tm = mx[0];
    tm = fmaxf(tm, __shfl_xor(tm, 32));

    // ---- defer-max (THR=8) ----
    if (!__all(tm <= mrun + 8.f)) {
      float mn = fmaxf(mrun, tm);
      float sfv = __expf(mrun - mn);
      mrun = mn;
      lrun *= sfv;
#pragma unroll
      for (int r = 0; r < 16; ++r) { ov0[r] *= sfv; ov1[r] *= sfv; }
    }

    // ---- exp + row sum ----
#pragma unroll
    for (int r = 0; r < 16; ++r) {
      p0[r] = __expf(p0[r] - mrun);
      p1[r] = __expf(p1[r] - mrun);
    }
    float sm[16];
#pragma unroll
    for (int r = 0; r < 16; ++r) sm[r] = p0[r] + p1[r];
#pragma unroll
    for (int s = 8; s > 0; s >>= 1)
#pragma unroll
      for (int r = 0; r < s; ++r) sm[r] += sm[r + s];
    float rs = sm[0];
    rs += __shfl_xor(rs, 32);
    lrun += rs;

    // ---- pack P -> PV B-frags (plain f2bf; no asm, no union, no ptr-select) --
    // pk[c][e] = P[64t + 16c + (e&3)+8(e>>2)+4hi][qg]
    bf16x8 pk[4];
#pragma unroll
    for (int c = 0; c < 4; ++c) {
      const int rb = 8 * (c & 1);
#pragma unroll
      for (int e = 0; e < 8; ++e) {
        float pv = (c < 2) ? p0[rb + e] : p1[rb + e];
        pk[c][e] = (short)f2bf(pv);
      }
    }

    // ---- PV: O^T[d][q], A = V^T frag (LDS), B = P ----
#pragma unroll
    for (int c = 0; c < 4; ++c) {
      const int slot = ((2 * c + hi) ^ (l5 & 7)) * 8;
      bf16x8 vt0 = *(const bf16x8*)&Vlds[cur][l5 * 64 + slot];
      bf16x8 vt1 = *(const bf16x8*)&Vlds[cur][(32 + l5) * 64 + slot];
      ov0 = __builtin_amdgcn_mfma_f32_32x32x16_bf16(vt0, pk[c], ov0, 0, 0, 0);
      ov1 = __builtin_amdgcn_mfma_f32_32x32x16_bf16(vt1, pk[c], ov1, 0, 0, 0);
    }
  }

  // ---- epilogue: O^T regs -> ctx[q][d], d = ds*32 + (r&3)+8(r>>2)+4hi ----
  const float invl = 1.0f / lrun;
  const size_t rowb = (size_t)(bb * S_ + qg) * 1024 + h * 64;
#pragma unroll
  for (int g = 0; g < 4; ++g) {
    u16x4 a, b;
#pragma unroll
    for (int j = 0; j < 4; ++j) {
      a[j] = f2bf(ov0[4 * g + j] * invl);
      b[j] = f2bf(ov1[4 * g + j] * invl);
    }
    *(u16x4*)&ctxb[rowb + 8 * g + 4 * hi] = a;
    *(u16x4*)&ctxb[rowb + 32 + 8 * g + 4 * hi] = b;
  }
}

extern "C" void kernel_launch(void* const* d_in, const int* in_sizes, int n_in,
                              void* d_out, int out_size, void* d_ws, size_t ws_size,
                              hipStream_t stream) {
  const float* hs      = (const float*)d_in[0];
  const float* w_qkv   = (const float*)d_in[1];
  const float* b_qkv   = (const float*)d_in[2];
  const float* w_dense = (const float*)d_in[3];
  const float* b_dense = (const float*)d_in[4];
  const float* rtab    = (const float*)d_in[5];
  float* out = (float*)d_out;

  char* ws = (char*)d_ws;
  unsigned short* qkvb = (unsigned short*)ws;                          // 24 MB
  unsigned short* ctxb = (unsigned short*)(ws + (((size_t)24) << 20)); // 8 MB
  unsigned short* hsb  = (unsigned short*)(ws + (((size_t)32) << 20)); // 8 MB
  unsigned short* wqT  = (unsigned short*)(ws + (((size_t)40) << 20)); // 6 MB
  unsigned short* wdT  = (unsigned short*)(ws + (((size_t)46) << 20)); // 2 MB
  unsigned short* vP   = (unsigned short*)(ws + (((size_t)48) << 20)); // 8 MB
  float* biasTab       = (float*)(ws + (((size_t)56) << 20));          // 256 KB

  hipLaunchKernelGGL(bias_table_kernel, dim3(256), dim3(256), 0, stream,
                     rtab, biasTab);
  hipLaunchKernelGGL(cvt_bf16_kernel, dim3(2048), dim3(256), 0, stream,
                     hs, hsb, 4096 * 1024 / 8);
  hipLaunchKernelGGL(transpose_cvt_kernel, dim3(48, 16), dim3(256), 0, stream,
                     w_qkv, wqT, 1024, 3072);
  hipLaunchKernelGGL(transpose_cvt_kernel, dim3(16, 16), dim3(256), 0, stream,
                     w_dense, wdT, 1024, 1024);
  hipLaunchKernelGGL((gemm_mfma_kernel<true>), dim3(24, 32), dim3(256), 0, stream,
                     hsb, wqT, b_qkv, (void*)qkvb, 4096, 3072, 1024);
  hipLaunchKernelGGL(vperm_kernel, dim3(32, 16, 2), dim3(256), 0, stream,
                     qkvb, vP);
  hipLaunchKernelGGL(attn_mfma5_kernel, dim3(512), dim3(256), 0, stream,
                     qkvb, vP, biasTab, ctxb);
  hipLaunchKernelGGL((gemm_mfma_kernel<false>), dim3(8, 32), dim3(256), 0, stream,
                     ctxb, wdT, b_dense, (void*)out, 4096, 1024, 1024);
}

// Round 10
// 146.774 us; speedup vs baseline: 1.1223x; 1.1223x over previous
//
#include <hip/hip_runtime.h>
#include <hip/hip_bf16.h>
#include <math.h>

#define S_ 2048

typedef __attribute__((ext_vector_type(8))) short bf16x8;
typedef __attribute__((ext_vector_type(4))) float f32x4;
typedef __attribute__((ext_vector_type(8))) unsigned short u16x8;
typedef __attribute__((ext_vector_type(4))) unsigned short u16x4;

__device__ inline unsigned short f2bf(float f) {
  union { float f; unsigned u; } x; x.f = f;
  unsigned r = x.u + 0x7fff + ((x.u >> 16) & 1);
  return (unsigned short)(r >> 16);
}

__device__ __forceinline__ float exp2_raw(float x) {
  float r;
  asm("v_exp_f32 %0, %1" : "=v"(r) : "v"(x));
  return r;
}

__device__ __forceinline__ void gll16(const unsigned short* g, unsigned short* l) {
  __builtin_amdgcn_global_load_lds(
      (const __attribute__((address_space(1))) unsigned int*)g,
      (__attribute__((address_space(3))) unsigned int*)l, 16, 0, 0);
}

// ------- bias table (pre-scaled by log2e): bias[h][rel + 2047], rel = k - q ---
__global__ void bias_table_kernel(const float* __restrict__ table,
                                  float* __restrict__ biasTab) {
  int idx = blockIdx.x * blockDim.x + threadIdx.x;
  if (idx >= 16 * 4096) return;
  int h = idx >> 12;
  int r = idx & 4095;
  int rel = r - 2047;                  // mem - ctx
  int bucket = rel > 0 ? 16 : 0;
  int ar = rel < 0 ? -rel : rel;
  if (ar < 8) {
    bucket += ar;
  } else {
    float tmp = logf((float)ar / 8.0f);
    float lf = tmp / 2.7725887222397811f * 8.0f;
    int large = 8 + (int)lf;
    bucket += (large < 15 ? large : 15);
  }
  biasTab[idx] = table[h * 32 + bucket] * 1.44269504088896f;  // log2e domain
}

// ---------------- fp32 -> bf16 elementwise (8 per thread) ----------------
__global__ __launch_bounds__(256) void cvt_bf16_kernel(
    const float* __restrict__ in, unsigned short* __restrict__ out, int n8) {
  int i = blockIdx.x * blockDim.x + threadIdx.x;
  if (i >= n8) return;
  float4 a = ((const float4*)in)[i * 2];
  float4 b = ((const float4*)in)[i * 2 + 1];
  u16x8 o;
  o[0] = f2bf(a.x); o[1] = f2bf(a.y); o[2] = f2bf(a.z); o[3] = f2bf(a.w);
  o[4] = f2bf(b.x); o[5] = f2bf(b.y); o[6] = f2bf(b.z); o[7] = f2bf(b.w);
  *(u16x8*)&out[(size_t)i * 8] = o;
}

// ---------------- fp32 [K][N] -> bf16 [N][K] transpose ----------------
__global__ __launch_bounds__(256) void transpose_cvt_kernel(
    const float* __restrict__ in, unsigned short* __restrict__ out,
    int K, int N) {
  __shared__ unsigned short tile[64][72];
  const int k0 = blockIdx.y * 64, n0 = blockIdx.x * 64;
  const int tid = threadIdx.x;
  const int rr = tid >> 4, cc = (tid & 15) * 4;
#pragma unroll
  for (int p = 0; p < 4; ++p) {
    int k = rr + p * 16;
    float4 v = *(const float4*)&in[(size_t)(k0 + k) * N + n0 + cc];
    tile[k][cc + 0] = f2bf(v.x);
    tile[k][cc + 1] = f2bf(v.y);
    tile[k][cc + 2] = f2bf(v.z);
    tile[k][cc + 3] = f2bf(v.w);
  }
  __syncthreads();
#pragma unroll
  for (int p = 0; p < 4; ++p) {
    int n = rr + p * 16;
    u16x4 o;
    o[0] = tile[cc + 0][n];
    o[1] = tile[cc + 1][n];
    o[2] = tile[cc + 2][n];
    o[3] = tile[cc + 3][n];
    *(u16x4*)&out[(size_t)(n0 + n) * K + k0 + cc] = o;
  }
}

// ---------------- bf16 MFMA GEMM: C[M][N] = A[M][K] @ Bt[N][K]^T + bias ------
template <bool BF16OUT>
__global__ __launch_bounds__(256) void gemm_mfma_kernel(
    const unsigned short* __restrict__ A, const unsigned short* __restrict__ Bt,
    const float* __restrict__ bias, void* __restrict__ Cout,
    int M, int N, int K) {
  __shared__ __align__(16) unsigned short As[128 * 32];
  __shared__ __align__(16) unsigned short Bs[128 * 32];
  const int tid = threadIdx.x;
  const int wave = tid >> 6, lane = tid & 63;
  const int lg = lane >> 4, lr = lane & 15;
  const int m0 = blockIdx.y * 128, n0 = blockIdx.x * 128;
  const int wm = (wave & 1) * 64, wn = (wave >> 1) * 64;

  f32x4 acc[4][4] = {};

  const int r0 = tid >> 2;
  const int sw = ((tid & 3) ^ (r0 & 3)) << 3;
  const unsigned short* aP0 = A + (size_t)(m0 + r0) * K + sw;
  const unsigned short* aP1 = A + (size_t)(m0 + 64 + r0) * K + sw;
  const unsigned short* bP0 = Bt + (size_t)(n0 + r0) * K + sw;
  const unsigned short* bP1 = Bt + (size_t)(n0 + 64 + r0) * K + sw;
  unsigned short* ldsA0 = &As[(tid & ~63) * 8];
  unsigned short* ldsA1 = &As[(256 + (tid & ~63)) * 8];
  unsigned short* ldsB0 = &Bs[(tid & ~63) * 8];
  unsigned short* ldsB1 = &Bs[(256 + (tid & ~63)) * 8];

  const int swz = (lg ^ (lr & 3)) << 3;

  for (int kt = 0; kt < K; kt += 32) {
    __syncthreads();
    gll16(aP0 + kt, ldsA0);
    gll16(aP1 + kt, ldsA1);
    gll16(bP0 + kt, ldsB0);
    gll16(bP1 + kt, ldsB1);
    __syncthreads();
    bf16x8 af[4], bfr[4];
#pragma unroll
    for (int t = 0; t < 4; ++t) {
      af[t]  = *(const bf16x8*)&As[(wm + t * 16 + lr) * 32 + swz];
      bfr[t] = *(const bf16x8*)&Bs[(wn + t * 16 + lr) * 32 + swz];
    }
#pragma unroll
    for (int i = 0; i < 4; ++i)
#pragma unroll
      for (int j = 0; j < 4; ++j)
        acc[i][j] = __builtin_amdgcn_mfma_f32_16x16x32_bf16(
            af[i], bfr[j], acc[i][j], 0, 0, 0);
  }

  float bv[4];
#pragma unroll
  for (int j = 0; j < 4; ++j) bv[j] = bias[n0 + wn + j * 16 + lr];
#pragma unroll
  for (int i = 0; i < 4; ++i) {
#pragma unroll
    for (int j = 0; j < 4; ++j) {
#pragma unroll
      for (int r = 0; r < 4; ++r) {
        int row = m0 + wm + i * 16 + lg * 4 + r;
        int col = n0 + wn + j * 16 + lr;
        float val = acc[i][j][r] + bv[j];
        if constexpr (BF16OUT)
          ((unsigned short*)Cout)[(size_t)row * N + col] = f2bf(val);
        else
          ((float*)Cout)[(size_t)row * N + col] = val;
      }
    }
  }
}

// ---------------- V permute pre-pass (16x16 kappa order, round-7 version) ----
// vP[bb][h][d][k'] : per 64-k tile t, 16B-slot phys_s = s ^ (d&7), slot s=4w+lg
// holds elems e=0..7 with k_within = w*32 + (e>>2)*16 + lg*4 + (e&3).
__global__ __launch_bounds__(256) void vperm_kernel(
    const unsigned short* __restrict__ qkvb, unsigned short* __restrict__ vP) {
  const int t = blockIdx.x, h = blockIdx.y, bb = blockIdx.z;
  __shared__ unsigned short tile[64][72];
  const int tid = threadIdx.x;
  {
    int k = tid >> 2, c = (tid & 3) * 16;
    const unsigned short* src =
        qkvb + (size_t)(bb * S_ + t * 64 + k) * 3072 + 2048 + h * 64 + c;
    *(bf16x8*)&tile[k][c] = *(const bf16x8*)src;
    *(bf16x8*)&tile[k][c + 8] = *(const bf16x8*)(src + 8);
  }
  __syncthreads();
  const int d = tid >> 2, m0 = (tid & 3) * 16;
  unsigned short* dst =
      vP + ((size_t)((bb * 16 + h) * 64 + d)) * S_ + t * 64 + m0;
#pragma unroll
  for (int half = 0; half < 2; ++half) {
    u16x8 o;
#pragma unroll
    for (int j = 0; j < 8; ++j) {
      int m = m0 + half * 8 + j;
      int phys_s = m >> 3, e = m & 7;
      int s = phys_s ^ (d & 7);
      int w = s >> 2, lg = s & 3;
      int kw = w * 32 + (e >> 2) * 16 + lg * 4 + (e & 3);
      o[j] = tile[kw][d];
    }
    *(u16x8*)(dst + half * 8) = o;
  }
}

// ---------------- bf16 MFMA flash attention v6 ----------------
// v4 skeleton (8 waves x 16 q-rows, 16x16x32) + exp2-domain softmax,
// lazy row-max, per-lane partial lrun (no shuffles in common path).
__global__ __launch_bounds__(512) void attn_mfma6_kernel(
    const unsigned short* __restrict__ qkvb, const unsigned short* __restrict__ vP,
    const float* __restrict__ biasTab, unsigned short* __restrict__ ctxb) {
  // bijective XCD swizzle: 512 wgs, 64 per XCD
  const int wg0 = blockIdx.x;
  const int wg = (wg0 & 7) * 64 + (wg0 >> 3);
  const int qt = wg & 15;
  const int h  = (wg >> 4) & 15;
  const int bb = wg >> 8;

  const int tid = threadIdx.x;
  const int wave = tid >> 6;     // 0..7
  const int lane = tid & 63;
  const int lg = lane >> 4;
  const int lr = lane & 15;

  __shared__ __align__(16) unsigned short Klds[2][4096];  // [64 k][8 blk][8] swz
  __shared__ __align__(16) unsigned short Vlds[2][4096];  // [64 d][8 slot][8] swz
  __shared__ float biasW[2][192];

  const int q0 = qt * 128;
  const int qw = q0 + wave * 16;
  const float SCL = 0.125f * 1.44269504088896f;   // QK scale in log2e domain
  const float THR = 11.5415603f;                  // 8 * log2e

  // Q fragments (B operand): qf[kh] = Q[qw+lr][kh*32+lg*8 ..+7]
  bf16x8 qf[2];
#pragma unroll
  for (int kh = 0; kh < 2; ++kh)
    qf[kh] = *(const bf16x8*)(qkvb +
        (size_t)(bb * S_ + qw + lr) * 3072 + h * 64 + kh * 32 + lg * 8);

  float mrun = -1e30f;
  float lpart = 0.f;     // per-lane partial sum (combined in epilogue)
  f32x4 ov[4] = {};

  // ---- staging geometry: thread stages chunk c = tid (512 x 16B per tile) ----
  const int kk = tid >> 3, kpb = tid & 7;
  const unsigned short* kptr = qkvb + (size_t)(bb * S_ + kk) * 3072 + 1024 +
                               h * 64 + (kpb ^ (kk & 7)) * 8;
  const unsigned short* vptr = vP + ((size_t)((bb * 16 + h) * 64 + (tid >> 3))) * S_ +
                               (tid & 7) * 8;
  const float* btabH = biasTab + h * 4096 + 2047;

  auto nonuni = [&](int tt) {
    int rl = tt * 64 - q0;
    return !((rl - 127 >= 91) || (rl + 63 <= -91));
  };

  // ---- prologue: stage tile 0 ----
  gll16(kptr, &Klds[0][(tid & ~63) * 8]);
  gll16(vptr, &Vlds[0][(tid & ~63) * 8]);
  if (nonuni(0) && tid < 192) biasW[0][tid] = btabH[-q0 - 127 + tid];

  for (int t = 0; t < 32; ++t) {
    const int cur = t & 1;
    __syncthreads();   // drains gll16 (vmcnt) + bias writes; swaps buffers

    if (t < 31) {
      const size_t kadv = (size_t)(t + 1) * 64 * 3072;
      gll16(kptr + kadv, &Klds[cur ^ 1][(tid & ~63) * 8]);
      gll16(vptr + (t + 1) * 64, &Vlds[cur ^ 1][(tid & ~63) * 8]);
      if (nonuni(t + 1) && tid < 192)
        biasW[cur ^ 1][tid] = btabH[(t + 1) * 64 - q0 - 127 + tid];
    }

    // ---- QK^T swapped: sc[kt][r] = S[kb+kt*16+lg*4+r][qw+lr] ----
    f32x4 sc[4] = {};
#pragma unroll
    for (int kt = 0; kt < 4; ++kt) {
      const unsigned short* kr = &Klds[cur][(kt * 16 + lr) * 64];
      bf16x8 kf0 = *(const bf16x8*)(kr + ((lg)     ^ (lr & 7)) * 8);
      bf16x8 kf1 = *(const bf16x8*)(kr + ((4 + lg) ^ (lr & 7)) * 8);
      sc[kt] = __builtin_amdgcn_mfma_f32_16x16x32_bf16(kf0, qf[0], sc[kt], 0, 0, 0);
      sc[kt] = __builtin_amdgcn_mfma_f32_16x16x32_bf16(kf1, qf[1], sc[kt], 0, 0, 0);
    }

    // ---- bias (log2e domain) ----
    float pp[4][4];
    if (nonuni(t)) {
      const int bidx = 127 + lg * 4 - wave * 16 - lr;
#pragma unroll
      for (int kt = 0; kt < 4; ++kt)
#pragma unroll
        for (int r = 0; r < 4; ++r)
          pp[kt][r] = sc[kt][r] * SCL + biasW[cur][bidx + kt * 16 + r];
    } else {
      const float cb = btabH[t * 64 - q0];   // bucket saturated: tile-constant
#pragma unroll
      for (int kt = 0; kt < 4; ++kt)
#pragma unroll
        for (int r = 0; r < 4; ++r)
          pp[kt][r] = sc[kt][r] * SCL + cb;
    }

    // ---- lane-local max (tree, no shuffles) ----
    float mx[8];
#pragma unroll
    for (int i = 0; i < 8; ++i)
      mx[i] = fmaxf(pp[i >> 1][(i & 1) * 2], pp[i >> 1][(i & 1) * 2 + 1]);
    float m01 = fmaxf(mx[0], mx[1]), m23 = fmaxf(mx[2], mx[3]);
    float m45 = fmaxf(mx[4], mx[5]), m67 = fmaxf(mx[6], mx[7]);
    float tm = fmaxf(fmaxf(m01, m23), fmaxf(m45, m67));

    // ---- lazy row-max: shuffles + rescale only when some lane exceeds ----
    if (!__all(tm <= mrun + THR)) {
      tm = fmaxf(tm, __shfl_xor(tm, 16));
      tm = fmaxf(tm, __shfl_xor(tm, 32));
      float mn = fmaxf(mrun, tm);
      float sfv = exp2_raw(mrun - mn);
      mrun = mn;
      lpart *= sfv;
#pragma unroll
      for (int r = 0; r < 4; ++r) {
        float sq = __shfl(sfv, (lane & 48) | (lg * 4 + r));
#pragma unroll
        for (int db = 0; db < 4; ++db) ov[db][r] *= sq;
      }
    }

    // ---- exp2 + per-lane partial sum (tree, no shuffles) ----
#pragma unroll
    for (int kt = 0; kt < 4; ++kt)
#pragma unroll
      for (int r = 0; r < 4; ++r)
        pp[kt][r] = exp2_raw(pp[kt][r] - mrun);
    float s8[8];
#pragma unroll
    for (int i = 0; i < 8; ++i)
      s8[i] = pp[i >> 1][(i & 1) * 2] + pp[i >> 1][(i & 1) * 2 + 1];
    float s01 = s8[0] + s8[1], s23 = s8[2] + s8[3];
    float s45 = s8[4] + s8[5], s67 = s8[6] + s8[7];
    lpart += (s01 + s23) + (s45 + s67);

    // ---- pack P -> bf16 A-frags via v_cvt_pk_bf16_f32 (v4-proven) ----
    union { bf16x8 v; unsigned u[4]; } pk[2];
#pragma unroll
    for (int kh = 0; kh < 2; ++kh) {
      asm("v_cvt_pk_bf16_f32 %0, %1, %2"
          : "=v"(pk[kh].u[0]) : "v"(pp[2 * kh][0]), "v"(pp[2 * kh][1]));
      asm("v_cvt_pk_bf16_f32 %0, %1, %2"
          : "=v"(pk[kh].u[1]) : "v"(pp[2 * kh][2]), "v"(pp[2 * kh][3]));
      asm("v_cvt_pk_bf16_f32 %0, %1, %2"
          : "=v"(pk[kh].u[2]) : "v"(pp[2 * kh + 1][0]), "v"(pp[2 * kh + 1][1]));
      asm("v_cvt_pk_bf16_f32 %0, %1, %2"
          : "=v"(pk[kh].u[3]) : "v"(pp[2 * kh + 1][2]), "v"(pp[2 * kh + 1][3]));
    }

    // ---- V fragments (plain b128, same kappa permutation) + PV ----
#pragma unroll
    for (int kh = 0; kh < 2; ++kh)
#pragma unroll
      for (int db = 0; db < 4; ++db) {
        bf16x8 vf = *(const bf16x8*)&Vlds[cur][
            (db * 16 + lr) * 64 + ((4 * kh + lg) ^ (lr & 7)) * 8];
        ov[db] = __builtin_amdgcn_mfma_f32_16x16x32_bf16(
            pk[kh].v, vf, ov[db], 0, 0, 0);
      }
  }

  // ---- epilogue: combine per-lane partials, normalize, store ----
  float lsum = lpart;
  lsum += __shfl_xor(lsum, 16);
  lsum += __shfl_xor(lsum, 32);
  float invl = 1.0f / lsum;
#pragma unroll
  for (int r = 0; r < 4; ++r) {
    float iv = __shfl(invl, (lane & 48) | (lg * 4 + r));
    size_t row = (size_t)(bb * S_ + qw + lg * 4 + r);
#pragma unroll
    for (int db = 0; db < 4; ++db)
      ctxb[row * 1024 + h * 64 + db * 16 + lr] = f2bf(ov[db][r] * iv);
  }
}

extern "C" void kernel_launch(void* const* d_in, const int* in_sizes, int n_in,
                              void* d_out, int out_size, void* d_ws, size_t ws_size,
                              hipStream_t stream) {
  const float* hs      = (const float*)d_in[0];
  const float* w_qkv   = (const float*)d_in[1];
  const float* b_qkv   = (const float*)d_in[2];
  const float* w_dense = (const float*)d_in[3];
  const float* b_dense = (const float*)d_in[4];
  const float* rtab    = (const float*)d_in[5];
  float* out = (float*)d_out;

  char* ws = (char*)d_ws;
  unsigned short* qkvb = (unsigned short*)ws;                          // 24 MB
  unsigned short* ctxb = (unsigned short*)(ws + (((size_t)24) << 20)); // 8 MB
  unsigned short* hsb  = (unsigned short*)(ws + (((size_t)32) << 20)); // 8 MB
  unsigned short* wqT  = (unsigned short*)(ws + (((size_t)40) << 20)); // 6 MB
  unsigned short* wdT  = (unsigned short*)(ws + (((size_t)46) << 20)); // 2 MB
  unsigned short* vP   = (unsigned short*)(ws + (((size_t)48) << 20)); // 8 MB
  float* biasTab       = (float*)(ws + (((size_t)56) << 20));          // 256 KB

  hipLaunchKernelGGL(bias_table_kernel, dim3(256), dim3(256), 0, stream,
                     rtab, biasTab);
  hipLaunchKernelGGL(cvt_bf16_kernel, dim3(2048), dim3(256), 0, stream,
                     hs, hsb, 4096 * 1024 / 8);
  hipLaunchKernelGGL(transpose_cvt_kernel, dim3(48, 16), dim3(256), 0, stream,
                     w_qkv, wqT, 1024, 3072);
  hipLaunchKernelGGL(transpose_cvt_kernel, dim3(16, 16), dim3(256), 0, stream,
                     w_dense, wdT, 1024, 1024);
  hipLaunchKernelGGL((gemm_mfma_kernel<true>), dim3(24, 32), dim3(256), 0, stream,
                     hsb, wqT, b_qkv, (void*)qkvb, 4096, 3072, 1024);
  hipLaunchKernelGGL(vperm_kernel, dim3(32, 16, 2), dim3(256), 0, stream,
                     qkvb, vP);
  hipLaunchKernelGGL(attn_mfma6_kernel, dim3(512), dim3(512), 0, stream,
                     qkvb, vP, biasTab, ctxb);
  hipLaunchKernelGGL((gemm_mfma_kernel<false>), dim3(8, 32), dim3(256), 0, stream,
                     ctxb, wdT, b_dense, (void*)out, 4096, 1024, 1024);
}

// Round 11
// 136.017 us; speedup vs baseline: 1.2111x; 1.0791x over previous
//
#include <hip/hip_runtime.h>
#include <hip/hip_bf16.h>
#include <math.h>

#define S_ 2048

typedef __attribute__((ext_vector_type(8))) short bf16x8;
typedef __attribute__((ext_vector_type(4))) float f32x4;
typedef __attribute__((ext_vector_type(8))) unsigned short u16x8;
typedef __attribute__((ext_vector_type(4))) unsigned short u16x4;

__device__ inline unsigned short f2bf(float f) {
  union { float f; unsigned u; } x; x.f = f;
  unsigned r = x.u + 0x7fff + ((x.u >> 16) & 1);
  return (unsigned short)(r >> 16);
}

__device__ __forceinline__ float exp2_raw(float x) {
  float r;
  asm("v_exp_f32 %0, %1" : "=v"(r) : "v"(x));
  return r;
}

__device__ __forceinline__ void gll16(const unsigned short* g, unsigned short* l) {
  __builtin_amdgcn_global_load_lds(
      (const __attribute__((address_space(1))) unsigned int*)g,
      (__attribute__((address_space(3))) unsigned int*)l, 16, 0, 0);
}

// ---------------- fused prologue ----------------
// blocks [0,2048): cvt hs -> hsb (bf16)
// blocks [2048,2816): transpose w_qkv -> wqT
// blocks [2816,3072): transpose w_dense -> wdT
// blocks [3072,3328): bias table (log2e domain)
__device__ __forceinline__ void transpose_tile(
    const float* __restrict__ in, unsigned short* __restrict__ out,
    int K, int N, int bx, int by, int tid, unsigned short (*tile)[72]) {
  const int k0 = by * 64, n0 = bx * 64;
  const int rr = tid >> 4, cc = (tid & 15) * 4;
#pragma unroll
  for (int p = 0; p < 4; ++p) {
    int k = rr + p * 16;
    float4 v = *(const float4*)&in[(size_t)(k0 + k) * N + n0 + cc];
    tile[k][cc + 0] = f2bf(v.x);
    tile[k][cc + 1] = f2bf(v.y);
    tile[k][cc + 2] = f2bf(v.z);
    tile[k][cc + 3] = f2bf(v.w);
  }
  __syncthreads();
#pragma unroll
  for (int p = 0; p < 4; ++p) {
    int n = rr + p * 16;
    u16x4 o;
    o[0] = tile[cc + 0][n];
    o[1] = tile[cc + 1][n];
    o[2] = tile[cc + 2][n];
    o[3] = tile[cc + 3][n];
    *(u16x4*)&out[(size_t)(n0 + n) * K + k0 + cc] = o;
  }
}

__global__ __launch_bounds__(256) void prologue_kernel(
    const float* __restrict__ hs, unsigned short* __restrict__ hsb,
    const float* __restrict__ w_qkv, unsigned short* __restrict__ wqT,
    const float* __restrict__ w_dense, unsigned short* __restrict__ wdT,
    const float* __restrict__ table, float* __restrict__ biasTab) {
  __shared__ unsigned short tile[64][72];
  const int blk = blockIdx.x;
  const int tid = threadIdx.x;
  if (blk < 2048) {
    // ---- cvt hs -> bf16, 8 per thread ----
    int i = blk * 256 + tid;
    float4 a = ((const float4*)hs)[i * 2];
    float4 b = ((const float4*)hs)[i * 2 + 1];
    u16x8 o;
    o[0] = f2bf(a.x); o[1] = f2bf(a.y); o[2] = f2bf(a.z); o[3] = f2bf(a.w);
    o[4] = f2bf(b.x); o[5] = f2bf(b.y); o[6] = f2bf(b.z); o[7] = f2bf(b.w);
    *(u16x8*)&hsb[(size_t)i * 8] = o;
  } else if (blk < 2816) {
    int t = blk - 2048;
    transpose_tile(w_qkv, wqT, 1024, 3072, t % 48, t / 48, tid, tile);
  } else if (blk < 3072) {
    int t = blk - 2816;
    transpose_tile(w_dense, wdT, 1024, 1024, t % 16, t / 16, tid, tile);
  } else {
    int idx = (blk - 3072) * 256 + tid;
    int h = idx >> 12;
    int r = idx & 4095;
    int rel = r - 2047;
    int bucket = rel > 0 ? 16 : 0;
    int ar = rel < 0 ? -rel : rel;
    if (ar < 8) {
      bucket += ar;
    } else {
      float tmp = logf((float)ar / 8.0f);
      float lf = tmp / 2.7725887222397811f * 8.0f;
      int large = 8 + (int)lf;
      bucket += (large < 15 ? large : 15);
    }
    biasTab[idx] = table[h * 32 + bucket] * 1.44269504088896f;  // log2e domain
  }
}

// ---------------- bf16 MFMA GEMM: C[M][N] = A[M][K] @ Bt[N][K]^T + bias ------
// XCD-swizzled block mapping (grid.x*grid.y % 8 == 0 required).
template <bool BF16OUT>
__global__ __launch_bounds__(256) void gemm_mfma_kernel(
    const unsigned short* __restrict__ A, const unsigned short* __restrict__ Bt,
    const float* __restrict__ bias, void* __restrict__ Cout,
    int M, int N, int K) {
  __shared__ __align__(16) unsigned short As[128 * 32];
  __shared__ __align__(16) unsigned short Bs[128 * 32];
  const int tid = threadIdx.x;
  const int wave = tid >> 6, lane = tid & 63;
  const int lg = lane >> 4, lr = lane & 15;
  // bijective XCD swizzle
  const int nbx = gridDim.x;
  const int flat = blockIdx.y * nbx + blockIdx.x;
  const int cpx = (nbx * gridDim.y) >> 3;
  const int swzid = (flat & 7) * cpx + (flat >> 3);
  const int m0 = (swzid / nbx) * 128, n0 = (swzid % nbx) * 128;
  const int wm = (wave & 1) * 64, wn = (wave >> 1) * 64;

  f32x4 acc[4][4] = {};

  const int r0 = tid >> 2;
  const int sw = ((tid & 3) ^ (r0 & 3)) << 3;
  const unsigned short* aP0 = A + (size_t)(m0 + r0) * K + sw;
  const unsigned short* aP1 = A + (size_t)(m0 + 64 + r0) * K + sw;
  const unsigned short* bP0 = Bt + (size_t)(n0 + r0) * K + sw;
  const unsigned short* bP1 = Bt + (size_t)(n0 + 64 + r0) * K + sw;
  unsigned short* ldsA0 = &As[(tid & ~63) * 8];
  unsigned short* ldsA1 = &As[(256 + (tid & ~63)) * 8];
  unsigned short* ldsB0 = &Bs[(tid & ~63) * 8];
  unsigned short* ldsB1 = &Bs[(256 + (tid & ~63)) * 8];

  const int swz = (lg ^ (lr & 3)) << 3;

  for (int kt = 0; kt < K; kt += 32) {
    __syncthreads();
    gll16(aP0 + kt, ldsA0);
    gll16(aP1 + kt, ldsA1);
    gll16(bP0 + kt, ldsB0);
    gll16(bP1 + kt, ldsB1);
    __syncthreads();
    bf16x8 af[4], bfr[4];
#pragma unroll
    for (int t = 0; t < 4; ++t) {
      af[t]  = *(const bf16x8*)&As[(wm + t * 16 + lr) * 32 + swz];
      bfr[t] = *(const bf16x8*)&Bs[(wn + t * 16 + lr) * 32 + swz];
    }
    __builtin_amdgcn_s_setprio(1);
#pragma unroll
    for (int i = 0; i < 4; ++i)
#pragma unroll
      for (int j = 0; j < 4; ++j)
        acc[i][j] = __builtin_amdgcn_mfma_f32_16x16x32_bf16(
            af[i], bfr[j], acc[i][j], 0, 0, 0);
    __builtin_amdgcn_s_setprio(0);
  }

  float bv[4];
#pragma unroll
  for (int j = 0; j < 4; ++j) bv[j] = bias[n0 + wn + j * 16 + lr];
#pragma unroll
  for (int i = 0; i < 4; ++i) {
#pragma unroll
    for (int j = 0; j < 4; ++j) {
#pragma unroll
      for (int r = 0; r < 4; ++r) {
        int row = m0 + wm + i * 16 + lg * 4 + r;
        int col = n0 + wn + j * 16 + lr;
        float val = acc[i][j][r] + bv[j];
        if constexpr (BF16OUT)
          ((unsigned short*)Cout)[(size_t)row * N + col] = f2bf(val);
        else
          ((float*)Cout)[(size_t)row * N + col] = val;
      }
    }
  }
}

// ---------------- V permute pre-pass (16x16 kappa order) ----------------
// vP[bb][h][d][k'] : per 64-k tile t, 16B-slot phys_s = s ^ (d&7), slot s=4w+lg
// holds elems e=0..7 with k_within = w*32 + (e>>2)*16 + lg*4 + (e&3).
__global__ __launch_bounds__(256) void vperm_kernel(
    const unsigned short* __restrict__ qkvb, unsigned short* __restrict__ vP) {
  const int t = blockIdx.x, h = blockIdx.y, bb = blockIdx.z;
  __shared__ unsigned short tile[64][72];
  const int tid = threadIdx.x;
  {
    int k = tid >> 2, c = (tid & 3) * 16;
    const unsigned short* src =
        qkvb + (size_t)(bb * S_ + t * 64 + k) * 3072 + 2048 + h * 64 + c;
    *(bf16x8*)&tile[k][c] = *(const bf16x8*)src;
    *(bf16x8*)&tile[k][c + 8] = *(const bf16x8*)(src + 8);
  }
  __syncthreads();
  const int d = tid >> 2, m0 = (tid & 3) * 16;
  unsigned short* dst =
      vP + ((size_t)((bb * 16 + h) * 64 + d)) * S_ + t * 64 + m0;
#pragma unroll
  for (int half = 0; half < 2; ++half) {
    u16x8 o;
#pragma unroll
    for (int j = 0; j < 8; ++j) {
      int m = m0 + half * 8 + j;
      int phys_s = m >> 3, e = m & 7;
      int s = phys_s ^ (d & 7);
      int w = s >> 2, lg = s & 3;
      int kw = w * 32 + (e >> 2) * 16 + lg * 4 + (e & 3);
      o[j] = tile[kw][d];
    }
    *(u16x8*)(dst + half * 8) = o;
  }
}

// ---------------- bf16 MFMA flash attention v6 + setprio ----------------
__global__ __launch_bounds__(512) void attn_mfma6_kernel(
    const unsigned short* __restrict__ qkvb, const unsigned short* __restrict__ vP,
    const float* __restrict__ biasTab, unsigned short* __restrict__ ctxb) {
  // bijective XCD swizzle: 512 wgs, 64 per XCD
  const int wg0 = blockIdx.x;
  const int wg = (wg0 & 7) * 64 + (wg0 >> 3);
  const int qt = wg & 15;
  const int h  = (wg >> 4) & 15;
  const int bb = wg >> 8;

  const int tid = threadIdx.x;
  const int wave = tid >> 6;     // 0..7
  const int lane = tid & 63;
  const int lg = lane >> 4;
  const int lr = lane & 15;

  __shared__ __align__(16) unsigned short Klds[2][4096];  // [64 k][8 blk][8] swz
  __shared__ __align__(16) unsigned short Vlds[2][4096];  // [64 d][8 slot][8] swz
  __shared__ float biasW[2][192];

  const int q0 = qt * 128;
  const int qw = q0 + wave * 16;
  const float SCL = 0.125f * 1.44269504088896f;   // QK scale in log2e domain
  const float THR = 11.5415603f;                  // 8 * log2e

  bf16x8 qf[2];
#pragma unroll
  for (int kh = 0; kh < 2; ++kh)
    qf[kh] = *(const bf16x8*)(qkvb +
        (size_t)(bb * S_ + qw + lr) * 3072 + h * 64 + kh * 32 + lg * 8);

  float mrun = -1e30f;
  float lpart = 0.f;
  f32x4 ov[4] = {};

  const int kk = tid >> 3, kpb = tid & 7;
  const unsigned short* kptr = qkvb + (size_t)(bb * S_ + kk) * 3072 + 1024 +
                               h * 64 + (kpb ^ (kk & 7)) * 8;
  const unsigned short* vptr = vP + ((size_t)((bb * 16 + h) * 64 + (tid >> 3))) * S_ +
                               (tid & 7) * 8;
  const float* btabH = biasTab + h * 4096 + 2047;

  auto nonuni = [&](int tt) {
    int rl = tt * 64 - q0;
    return !((rl - 127 >= 91) || (rl + 63 <= -91));
  };

  gll16(kptr, &Klds[0][(tid & ~63) * 8]);
  gll16(vptr, &Vlds[0][(tid & ~63) * 8]);
  if (nonuni(0) && tid < 192) biasW[0][tid] = btabH[-q0 - 127 + tid];

  for (int t = 0; t < 32; ++t) {
    const int cur = t & 1;
    __syncthreads();

    if (t < 31) {
      const size_t kadv = (size_t)(t + 1) * 64 * 3072;
      gll16(kptr + kadv, &Klds[cur ^ 1][(tid & ~63) * 8]);
      gll16(vptr + (t + 1) * 64, &Vlds[cur ^ 1][(tid & ~63) * 8]);
      if (nonuni(t + 1) && tid < 192)
        biasW[cur ^ 1][tid] = btabH[(t + 1) * 64 - q0 - 127 + tid];
    }

    // ---- QK^T swapped ----
    f32x4 sc[4] = {};
    __builtin_amdgcn_s_setprio(1);
#pragma unroll
    for (int kt = 0; kt < 4; ++kt) {
      const unsigned short* kr = &Klds[cur][(kt * 16 + lr) * 64];
      bf16x8 kf0 = *(const bf16x8*)(kr + ((lg)     ^ (lr & 7)) * 8);
      bf16x8 kf1 = *(const bf16x8*)(kr + ((4 + lg) ^ (lr & 7)) * 8);
      sc[kt] = __builtin_amdgcn_mfma_f32_16x16x32_bf16(kf0, qf[0], sc[kt], 0, 0, 0);
      sc[kt] = __builtin_amdgcn_mfma_f32_16x16x32_bf16(kf1, qf[1], sc[kt], 0, 0, 0);
    }
    __builtin_amdgcn_s_setprio(0);

    // ---- bias (log2e domain) ----
    float pp[4][4];
    if (nonuni(t)) {
      const int bidx = 127 + lg * 4 - wave * 16 - lr;
#pragma unroll
      for (int kt = 0; kt < 4; ++kt)
#pragma unroll
        for (int r = 0; r < 4; ++r)
          pp[kt][r] = sc[kt][r] * SCL + biasW[cur][bidx + kt * 16 + r];
    } else {
      const float cb = btabH[t * 64 - q0];
#pragma unroll
      for (int kt = 0; kt < 4; ++kt)
#pragma unroll
        for (int r = 0; r < 4; ++r)
          pp[kt][r] = sc[kt][r] * SCL + cb;
    }

    // ---- lane-local max (tree) ----
    float mx[8];
#pragma unroll
    for (int i = 0; i < 8; ++i)
      mx[i] = fmaxf(pp[i >> 1][(i & 1) * 2], pp[i >> 1][(i & 1) * 2 + 1]);
    float m01 = fmaxf(mx[0], mx[1]), m23 = fmaxf(mx[2], mx[3]);
    float m45 = fmaxf(mx[4], mx[5]), m67 = fmaxf(mx[6], mx[7]);
    float tm = fmaxf(fmaxf(m01, m23), fmaxf(m45, m67));

    // ---- lazy row-max ----
    if (!__all(tm <= mrun + THR)) {
      tm = fmaxf(tm, __shfl_xor(tm, 16));
      tm = fmaxf(tm, __shfl_xor(tm, 32));
      float mn = fmaxf(mrun, tm);
      float sfv = exp2_raw(mrun - mn);
      mrun = mn;
      lpart *= sfv;
#pragma unroll
      for (int r = 0; r < 4; ++r) {
        float sq = __shfl(sfv, (lane & 48) | (lg * 4 + r));
#pragma unroll
        for (int db = 0; db < 4; ++db) ov[db][r] *= sq;
      }
    }

    // ---- exp2 + per-lane partial sum ----
#pragma unroll
    for (int kt = 0; kt < 4; ++kt)
#pragma unroll
      for (int r = 0; r < 4; ++r)
        pp[kt][r] = exp2_raw(pp[kt][r] - mrun);
    float s8[8];
#pragma unroll
    for (int i = 0; i < 8; ++i)
      s8[i] = pp[i >> 1][(i & 1) * 2] + pp[i >> 1][(i & 1) * 2 + 1];
    float s01 = s8[0] + s8[1], s23 = s8[2] + s8[3];
    float s45 = s8[4] + s8[5], s67 = s8[6] + s8[7];
    lpart += (s01 + s23) + (s45 + s67);

    // ---- pack P via v_cvt_pk_bf16_f32 ----
    union { bf16x8 v; unsigned u[4]; } pk[2];
#pragma unroll
    for (int kh = 0; kh < 2; ++kh) {
      asm("v_cvt_pk_bf16_f32 %0, %1, %2"
          : "=v"(pk[kh].u[0]) : "v"(pp[2 * kh][0]), "v"(pp[2 * kh][1]));
      asm("v_cvt_pk_bf16_f32 %0, %1, %2"
          : "=v"(pk[kh].u[1]) : "v"(pp[2 * kh][2]), "v"(pp[2 * kh][3]));
      asm("v_cvt_pk_bf16_f32 %0, %1, %2"
          : "=v"(pk[kh].u[2]) : "v"(pp[2 * kh + 1][0]), "v"(pp[2 * kh + 1][1]));
      asm("v_cvt_pk_bf16_f32 %0, %1, %2"
          : "=v"(pk[kh].u[3]) : "v"(pp[2 * kh + 1][2]), "v"(pp[2 * kh + 1][3]));
    }

    // ---- PV ----
    __builtin_amdgcn_s_setprio(1);
#pragma unroll
    for (int kh = 0; kh < 2; ++kh)
#pragma unroll
      for (int db = 0; db < 4; ++db) {
        bf16x8 vf = *(const bf16x8*)&Vlds[cur][
            (db * 16 + lr) * 64 + ((4 * kh + lg) ^ (lr & 7)) * 8];
        ov[db] = __builtin_amdgcn_mfma_f32_16x16x32_bf16(
            pk[kh].v, vf, ov[db], 0, 0, 0);
      }
    __builtin_amdgcn_s_setprio(0);
  }

  // ---- epilogue ----
  float lsum = lpart;
  lsum += __shfl_xor(lsum, 16);
  lsum += __shfl_xor(lsum, 32);
  float invl = 1.0f / lsum;
#pragma unroll
  for (int r = 0; r < 4; ++r) {
    float iv = __shfl(invl, (lane & 48) | (lg * 4 + r));
    size_t row = (size_t)(bb * S_ + qw + lg * 4 + r);
#pragma unroll
    for (int db = 0; db < 4; ++db)
      ctxb[row * 1024 + h * 64 + db * 16 + lr] = f2bf(ov[db][r] * iv);
  }
}

extern "C" void kernel_launch(void* const* d_in, const int* in_sizes, int n_in,
                              void* d_out, int out_size, void* d_ws, size_t ws_size,
                              hipStream_t stream) {
  const float* hs      = (const float*)d_in[0];
  const float* w_qkv   = (const float*)d_in[1];
  const float* b_qkv   = (const float*)d_in[2];
  const float* w_dense = (const float*)d_in[3];
  const float* b_dense = (const float*)d_in[4];
  const float* rtab    = (const float*)d_in[5];
  float* out = (float*)d_out;

  char* ws = (char*)d_ws;
  unsigned short* qkvb = (unsigned short*)ws;                          // 24 MB
  unsigned short* ctxb = (unsigned short*)(ws + (((size_t)24) << 20)); // 8 MB
  unsigned short* hsb  = (unsigned short*)(ws + (((size_t)32) << 20)); // 8 MB
  unsigned short* wqT  = (unsigned short*)(ws + (((size_t)40) << 20)); // 6 MB
  unsigned short* wdT  = (unsigned short*)(ws + (((size_t)46) << 20)); // 2 MB
  unsigned short* vP   = (unsigned short*)(ws + (((size_t)48) << 20)); // 8 MB
  float* biasTab       = (float*)(ws + (((size_t)56) << 20));          // 256 KB

  hipLaunchKernelGGL(prologue_kernel, dim3(3328), dim3(256), 0, stream,
                     hs, hsb, w_qkv, wqT, w_dense, wdT, rtab, biasTab);
  hipLaunchKernelGGL((gemm_mfma_kernel<true>), dim3(24, 32), dim3(256), 0, stream,
                     hsb, wqT, b_qkv, (void*)qkvb, 4096, 3072, 1024);
  hipLaunchKernelGGL(vperm_kernel, dim3(32, 16, 2), dim3(256), 0, stream,
                     qkvb, vP);
  hipLaunchKernelGGL(attn_mfma6_kernel, dim3(512), dim3(512), 0, stream,
                     qkvb, vP, biasTab, ctxb);
  hipLaunchKernelGGL((gemm_mfma_kernel<false>), dim3(8, 32), dim3(256), 0, stream,
                     ctxb, wdT, b_dense, (void*)out, 4096, 1024, 1024);
}

// Round 12
// 134.099 us; speedup vs baseline: 1.2284x; 1.0143x over previous
//
#include <hip/hip_runtime.h>
#include <hip/hip_bf16.h>
#include <math.h>

#define S_ 2048

typedef __attribute__((ext_vector_type(8))) short bf16x8;
typedef __attribute__((ext_vector_type(4))) float f32x4;
typedef __attribute__((ext_vector_type(8))) unsigned short u16x8;
typedef __attribute__((ext_vector_type(4))) unsigned short u16x4;

__device__ inline unsigned short f2bf(float f) {
  union { float f; unsigned u; } x; x.f = f;
  unsigned r = x.u + 0x7fff + ((x.u >> 16) & 1);
  return (unsigned short)(r >> 16);
}

__device__ __forceinline__ float exp2_raw(float x) {
  float r;
  asm("v_exp_f32 %0, %1" : "=v"(r) : "v"(x));
  return r;
}

__device__ __forceinline__ void gll16(const unsigned short* g, unsigned short* l) {
  __builtin_amdgcn_global_load_lds(
      (const __attribute__((address_space(1))) unsigned int*)g,
      (__attribute__((address_space(3))) unsigned int*)l, 16, 0, 0);
}

// ---------------- fused prologue ----------------
// blocks [0,2048): cvt hs -> hsb (bf16)
// blocks [2048,2816): transpose w_qkv -> wqT
// blocks [2816,3072): transpose w_dense -> wdT
// blocks [3072,3328): bias table (log2e domain)
__device__ __forceinline__ void transpose_tile(
    const float* __restrict__ in, unsigned short* __restrict__ out,
    int K, int N, int bx, int by, int tid, unsigned short (*tile)[72]) {
  const int k0 = by * 64, n0 = bx * 64;
  const int rr = tid >> 4, cc = (tid & 15) * 4;
#pragma unroll
  for (int p = 0; p < 4; ++p) {
    int k = rr + p * 16;
    float4 v = *(const float4*)&in[(size_t)(k0 + k) * N + n0 + cc];
    tile[k][cc + 0] = f2bf(v.x);
    tile[k][cc + 1] = f2bf(v.y);
    tile[k][cc + 2] = f2bf(v.z);
    tile[k][cc + 3] = f2bf(v.w);
  }
  __syncthreads();
#pragma unroll
  for (int p = 0; p < 4; ++p) {
    int n = rr + p * 16;
    u16x4 o;
    o[0] = tile[cc + 0][n];
    o[1] = tile[cc + 1][n];
    o[2] = tile[cc + 2][n];
    o[3] = tile[cc + 3][n];
    *(u16x4*)&out[(size_t)(n0 + n) * K + k0 + cc] = o;
  }
}

__global__ __launch_bounds__(256) void prologue_kernel(
    const float* __restrict__ hs, unsigned short* __restrict__ hsb,
    const float* __restrict__ w_qkv, unsigned short* __restrict__ wqT,
    const float* __restrict__ w_dense, unsigned short* __restrict__ wdT,
    const float* __restrict__ table, float* __restrict__ biasTab) {
  __shared__ unsigned short tile[64][72];
  const int blk = blockIdx.x;
  const int tid = threadIdx.x;
  if (blk < 2048) {
    int i = blk * 256 + tid;
    float4 a = ((const float4*)hs)[i * 2];
    float4 b = ((const float4*)hs)[i * 2 + 1];
    u16x8 o;
    o[0] = f2bf(a.x); o[1] = f2bf(a.y); o[2] = f2bf(a.z); o[3] = f2bf(a.w);
    o[4] = f2bf(b.x); o[5] = f2bf(b.y); o[6] = f2bf(b.z); o[7] = f2bf(b.w);
    *(u16x8*)&hsb[(size_t)i * 8] = o;
  } else if (blk < 2816) {
    int t = blk - 2048;
    transpose_tile(w_qkv, wqT, 1024, 3072, t % 48, t / 48, tid, tile);
  } else if (blk < 3072) {
    int t = blk - 2816;
    transpose_tile(w_dense, wdT, 1024, 1024, t % 16, t / 16, tid, tile);
  } else {
    int idx = (blk - 3072) * 256 + tid;
    int h = idx >> 12;
    int r = idx & 4095;
    int rel = r - 2047;
    int bucket = rel > 0 ? 16 : 0;
    int ar = rel < 0 ? -rel : rel;
    if (ar < 8) {
      bucket += ar;
    } else {
      float tmp = logf((float)ar / 8.0f);
      float lf = tmp / 2.7725887222397811f * 8.0f;
      int large = 8 + (int)lf;
      bucket += (large < 15 ? large : 15);
    }
    biasTab[idx] = table[h * 32 + bucket] * 1.44269504088896f;  // log2e domain
  }
}

// ------- bf16 MFMA GEMM, 128x128 tile: C = A @ Bt^T + bias (XCD-swizzled) ----
template <bool BF16OUT>
__global__ __launch_bounds__(256) void gemm_mfma_kernel(
    const unsigned short* __restrict__ A, const unsigned short* __restrict__ Bt,
    const float* __restrict__ bias, void* __restrict__ Cout,
    int M, int N, int K) {
  __shared__ __align__(16) unsigned short As[128 * 32];
  __shared__ __align__(16) unsigned short Bs[128 * 32];
  const int tid = threadIdx.x;
  const int wave = tid >> 6, lane = tid & 63;
  const int lg = lane >> 4, lr = lane & 15;
  const int nbx = gridDim.x;
  const int flat = blockIdx.y * nbx + blockIdx.x;
  const int cpx = (nbx * gridDim.y) >> 3;
  const int swzid = (flat & 7) * cpx + (flat >> 3);
  const int m0 = (swzid / nbx) * 128, n0 = (swzid % nbx) * 128;
  const int wm = (wave & 1) * 64, wn = (wave >> 1) * 64;

  f32x4 acc[4][4] = {};

  const int r0 = tid >> 2;
  const int sw = ((tid & 3) ^ (r0 & 3)) << 3;
  const unsigned short* aP0 = A + (size_t)(m0 + r0) * K + sw;
  const unsigned short* aP1 = A + (size_t)(m0 + 64 + r0) * K + sw;
  const unsigned short* bP0 = Bt + (size_t)(n0 + r0) * K + sw;
  const unsigned short* bP1 = Bt + (size_t)(n0 + 64 + r0) * K + sw;
  unsigned short* ldsA0 = &As[(tid & ~63) * 8];
  unsigned short* ldsA1 = &As[(256 + (tid & ~63)) * 8];
  unsigned short* ldsB0 = &Bs[(tid & ~63) * 8];
  unsigned short* ldsB1 = &Bs[(256 + (tid & ~63)) * 8];

  const int swz = (lg ^ (lr & 3)) << 3;

  for (int kt = 0; kt < K; kt += 32) {
    __syncthreads();
    gll16(aP0 + kt, ldsA0);
    gll16(aP1 + kt, ldsA1);
    gll16(bP0 + kt, ldsB0);
    gll16(bP1 + kt, ldsB1);
    __syncthreads();
    bf16x8 af[4], bfr[4];
#pragma unroll
    for (int t = 0; t < 4; ++t) {
      af[t]  = *(const bf16x8*)&As[(wm + t * 16 + lr) * 32 + swz];
      bfr[t] = *(const bf16x8*)&Bs[(wn + t * 16 + lr) * 32 + swz];
    }
#pragma unroll
    for (int i = 0; i < 4; ++i)
#pragma unroll
      for (int j = 0; j < 4; ++j)
        acc[i][j] = __builtin_amdgcn_mfma_f32_16x16x32_bf16(
            af[i], bfr[j], acc[i][j], 0, 0, 0);
  }

  float bv[4];
#pragma unroll
  for (int j = 0; j < 4; ++j) bv[j] = bias[n0 + wn + j * 16 + lr];
#pragma unroll
  for (int i = 0; i < 4; ++i) {
#pragma unroll
    for (int j = 0; j < 4; ++j) {
#pragma unroll
      for (int r = 0; r < 4; ++r) {
        int row = m0 + wm + i * 16 + lg * 4 + r;
        int col = n0 + wn + j * 16 + lr;
        float val = acc[i][j][r] + bv[j];
        if constexpr (BF16OUT)
          ((unsigned short*)Cout)[(size_t)row * N + col] = f2bf(val);
        else
          ((float*)Cout)[(size_t)row * N + col] = val;
      }
    }
  }
}

// ------- bf16 MFMA GEMM, 64x128 tile (2x occupancy for small-grid shapes) ----
// 4 waves 2x2 of 32x64. grid (N/128, M/64), product % 8 == 0.
template <bool BF16OUT>
__global__ __launch_bounds__(256) void gemm_mfma64_kernel(
    const unsigned short* __restrict__ A, const unsigned short* __restrict__ Bt,
    const float* __restrict__ bias, void* __restrict__ Cout,
    int M, int N, int K) {
  __shared__ __align__(16) unsigned short As[64 * 32];
  __shared__ __align__(16) unsigned short Bs[128 * 32];
  const int tid = threadIdx.x;
  const int wave = tid >> 6, lane = tid & 63;
  const int lg = lane >> 4, lr = lane & 15;
  const int nbx = gridDim.x;
  const int flat = blockIdx.y * nbx + blockIdx.x;
  const int cpx = (nbx * gridDim.y) >> 3;
  const int swzid = (flat & 7) * cpx + (flat >> 3);
  const int m0 = (swzid / nbx) * 64, n0 = (swzid % nbx) * 128;
  const int wm = (wave & 1) * 32, wn = (wave >> 1) * 64;

  f32x4 acc[2][4] = {};

  const int r0 = tid >> 2;
  const int sw = ((tid & 3) ^ (r0 & 3)) << 3;
  const unsigned short* aP  = A + (size_t)(m0 + r0) * K + sw;
  const unsigned short* bP0 = Bt + (size_t)(n0 + r0) * K + sw;
  const unsigned short* bP1 = Bt + (size_t)(n0 + 64 + r0) * K + sw;
  unsigned short* ldsA  = &As[(tid & ~63) * 8];
  unsigned short* ldsB0 = &Bs[(tid & ~63) * 8];
  unsigned short* ldsB1 = &Bs[(256 + (tid & ~63)) * 8];

  const int swz = (lg ^ (lr & 3)) << 3;

  for (int kt = 0; kt < K; kt += 32) {
    __syncthreads();
    gll16(aP + kt, ldsA);
    gll16(bP0 + kt, ldsB0);
    gll16(bP1 + kt, ldsB1);
    __syncthreads();
    bf16x8 af[2], bfr[4];
#pragma unroll
    for (int t = 0; t < 2; ++t)
      af[t] = *(const bf16x8*)&As[(wm + t * 16 + lr) * 32 + swz];
#pragma unroll
    for (int t = 0; t < 4; ++t)
      bfr[t] = *(const bf16x8*)&Bs[(wn + t * 16 + lr) * 32 + swz];
#pragma unroll
    for (int i = 0; i < 2; ++i)
#pragma unroll
      for (int j = 0; j < 4; ++j)
        acc[i][j] = __builtin_amdgcn_mfma_f32_16x16x32_bf16(
            af[i], bfr[j], acc[i][j], 0, 0, 0);
  }

  float bv[4];
#pragma unroll
  for (int j = 0; j < 4; ++j) bv[j] = bias[n0 + wn + j * 16 + lr];
#pragma unroll
  for (int i = 0; i < 2; ++i) {
#pragma unroll
    for (int j = 0; j < 4; ++j) {
#pragma unroll
      for (int r = 0; r < 4; ++r) {
        int row = m0 + wm + i * 16 + lg * 4 + r;
        int col = n0 + wn + j * 16 + lr;
        float val = acc[i][j][r] + bv[j];
        if constexpr (BF16OUT)
          ((unsigned short*)Cout)[(size_t)row * N + col] = f2bf(val);
        else
          ((float*)Cout)[(size_t)row * N + col] = val;
      }
    }
  }
}

// ---------------- V permute pre-pass (16x16 kappa order) ----------------
// vP[bb][h][d][k'] : per 64-k tile t, 16B-slot phys_s = s ^ (d&7), slot s=4w+lg
// holds elems e=0..7 with k_within = w*32 + (e>>2)*16 + lg*4 + (e&3).
__global__ __launch_bounds__(256) void vperm_kernel(
    const unsigned short* __restrict__ qkvb, unsigned short* __restrict__ vP) {
  const int t = blockIdx.x, h = blockIdx.y, bb = blockIdx.z;
  __shared__ unsigned short tile[64][72];
  const int tid = threadIdx.x;
  {
    int k = tid >> 2, c = (tid & 3) * 16;
    const unsigned short* src =
        qkvb + (size_t)(bb * S_ + t * 64 + k) * 3072 + 2048 + h * 64 + c;
    *(bf16x8*)&tile[k][c] = *(const bf16x8*)src;
    *(bf16x8*)&tile[k][c + 8] = *(const bf16x8*)(src + 8);
  }
  __syncthreads();
  const int d = tid >> 2, m0 = (tid & 3) * 16;
  unsigned short* dst =
      vP + ((size_t)((bb * 16 + h) * 64 + d)) * S_ + t * 64 + m0;
#pragma unroll
  for (int half = 0; half < 2; ++half) {
    u16x8 o;
#pragma unroll
    for (int j = 0; j < 8; ++j) {
      int m = m0 + half * 8 + j;
      int phys_s = m >> 3, e = m & 7;
      int s = phys_s ^ (d & 7);
      int w = s >> 2, lg = s & 3;
      int kw = w * 32 + (e >> 2) * 16 + lg * 4 + (e & 3);
      o[j] = tile[kw][d];
    }
    *(u16x8*)(dst + half * 8) = o;
  }
}

// ---------------- bf16 MFMA flash attention v6 ----------------
__global__ __launch_bounds__(512) void attn_mfma6_kernel(
    const unsigned short* __restrict__ qkvb, const unsigned short* __restrict__ vP,
    const float* __restrict__ biasTab, unsigned short* __restrict__ ctxb) {
  // bijective XCD swizzle: 512 wgs, 64 per XCD
  const int wg0 = blockIdx.x;
  const int wg = (wg0 & 7) * 64 + (wg0 >> 3);
  const int qt = wg & 15;
  const int h  = (wg >> 4) & 15;
  const int bb = wg >> 8;

  const int tid = threadIdx.x;
  const int wave = tid >> 6;     // 0..7
  const int lane = tid & 63;
  const int lg = lane >> 4;
  const int lr = lane & 15;

  __shared__ __align__(16) unsigned short Klds[2][4096];  // [64 k][8 blk][8] swz
  __shared__ __align__(16) unsigned short Vlds[2][4096];  // [64 d][8 slot][8] swz
  __shared__ float biasW[2][192];

  const int q0 = qt * 128;
  const int qw = q0 + wave * 16;
  const float SCL = 0.125f * 1.44269504088896f;   // QK scale in log2e domain
  const float THR = 11.5415603f;                  // 8 * log2e

  bf16x8 qf[2];
#pragma unroll
  for (int kh = 0; kh < 2; ++kh)
    qf[kh] = *(const bf16x8*)(qkvb +
        (size_t)(bb * S_ + qw + lr) * 3072 + h * 64 + kh * 32 + lg * 8);

  float mrun = -1e30f;
  float lpart = 0.f;
  f32x4 ov[4] = {};

  const int kk = tid >> 3, kpb = tid & 7;
  const unsigned short* kptr = qkvb + (size_t)(bb * S_ + kk) * 3072 + 1024 +
                               h * 64 + (kpb ^ (kk & 7)) * 8;
  const unsigned short* vptr = vP + ((size_t)((bb * 16 + h) * 64 + (tid >> 3))) * S_ +
                               (tid & 7) * 8;
  const float* btabH = biasTab + h * 4096 + 2047;

  auto nonuni = [&](int tt) {
    int rl = tt * 64 - q0;
    return !((rl - 127 >= 91) || (rl + 63 <= -91));
  };

  gll16(kptr, &Klds[0][(tid & ~63) * 8]);
  gll16(vptr, &Vlds[0][(tid & ~63) * 8]);
  if (nonuni(0) && tid < 192) biasW[0][tid] = btabH[-q0 - 127 + tid];

  for (int t = 0; t < 32; ++t) {
    const int cur = t & 1;
    __syncthreads();

    if (t < 31) {
      const size_t kadv = (size_t)(t + 1) * 64 * 3072;
      gll16(kptr + kadv, &Klds[cur ^ 1][(tid & ~63) * 8]);
      gll16(vptr + (t + 1) * 64, &Vlds[cur ^ 1][(tid & ~63) * 8]);
      if (nonuni(t + 1) && tid < 192)
        biasW[cur ^ 1][tid] = btabH[(t + 1) * 64 - q0 - 127 + tid];
    }

    // ---- QK^T swapped ----
    f32x4 sc[4] = {};
    __builtin_amdgcn_s_setprio(1);
#pragma unroll
    for (int kt = 0; kt < 4; ++kt) {
      const unsigned short* kr = &Klds[cur][(kt * 16 + lr) * 64];
      bf16x8 kf0 = *(const bf16x8*)(kr + ((lg)     ^ (lr & 7)) * 8);
      bf16x8 kf1 = *(const bf16x8*)(kr + ((4 + lg) ^ (lr & 7)) * 8);
      sc[kt] = __builtin_amdgcn_mfma_f32_16x16x32_bf16(kf0, qf[0], sc[kt], 0, 0, 0);
      sc[kt] = __builtin_amdgcn_mfma_f32_16x16x32_bf16(kf1, qf[1], sc[kt], 0, 0, 0);
    }
    __builtin_amdgcn_s_setprio(0);

    // ---- bias (log2e domain) ----
    float pp[4][4];
    if (nonuni(t)) {
      const int bidx = 127 + lg * 4 - wave * 16 - lr;
#pragma unroll
      for (int kt = 0; kt < 4; ++kt)
#pragma unroll
        for (int r = 0; r < 4; ++r)
          pp[kt][r] = sc[kt][r] * SCL + biasW[cur][bidx + kt * 16 + r];
    } else {
      const float cb = btabH[t * 64 - q0];
#pragma unroll
      for (int kt = 0; kt < 4; ++kt)
#pragma unroll
        for (int r = 0; r < 4; ++r)
          pp[kt][r] = sc[kt][r] * SCL + cb;
    }

    // ---- lane-local max (tree) ----
    float mx[8];
#pragma unroll
    for (int i = 0; i < 8; ++i)
      mx[i] = fmaxf(pp[i >> 1][(i & 1) * 2], pp[i >> 1][(i & 1) * 2 + 1]);
    float m01 = fmaxf(mx[0], mx[1]), m23 = fmaxf(mx[2], mx[3]);
    float m45 = fmaxf(mx[4], mx[5]), m67 = fmaxf(mx[6], mx[7]);
    float tm = fmaxf(fmaxf(m01, m23), fmaxf(m45, m67));

    // ---- lazy row-max ----
    if (!__all(tm <= mrun + THR)) {
      tm = fmaxf(tm, __shfl_xor(tm, 16));
      tm = fmaxf(tm, __shfl_xor(tm, 32));
      float mn = fmaxf(mrun, tm);
      float sfv = exp2_raw(mrun - mn);
      mrun = mn;
      lpart *= sfv;
#pragma unroll
      for (int r = 0; r < 4; ++r) {
        float sq = __shfl(sfv, (lane & 48) | (lg * 4 + r));
#pragma unroll
        for (int db = 0; db < 4; ++db) ov[db][r] *= sq;
      }
    }

    // ---- exp2 + per-lane partial sum ----
#pragma unroll
    for (int kt = 0; kt < 4; ++kt)
#pragma unroll
      for (int r = 0; r < 4; ++r)
        pp[kt][r] = exp2_raw(pp[kt][r] - mrun);
    float s8[8];
#pragma unroll
    for (int i = 0; i < 8; ++i)
      s8[i] = pp[i >> 1][(i & 1) * 2] + pp[i >> 1][(i & 1) * 2 + 1];
    float s01 = s8[0] + s8[1], s23 = s8[2] + s8[3];
    float s45 = s8[4] + s8[5], s67 = s8[6] + s8[7];
    lpart += (s01 + s23) + (s45 + s67);

    // ---- pack P via v_cvt_pk_bf16_f32 ----
    union { bf16x8 v; unsigned u[4]; } pk[2];
#pragma unroll
    for (int kh = 0; kh < 2; ++kh) {
      asm("v_cvt_pk_bf16_f32 %0, %1, %2"
          : "=v"(pk[kh].u[0]) : "v"(pp[2 * kh][0]), "v"(pp[2 * kh][1]));
      asm("v_cvt_pk_bf16_f32 %0, %1, %2"
          : "=v"(pk[kh].u[1]) : "v"(pp[2 * kh][2]), "v"(pp[2 * kh][3]));
      asm("v_cvt_pk_bf16_f32 %0, %1, %2"
          : "=v"(pk[kh].u[2]) : "v"(pp[2 * kh + 1][0]), "v"(pp[2 * kh + 1][1]));
      asm("v_cvt_pk_bf16_f32 %0, %1, %2"
          : "=v"(pk[kh].u[3]) : "v"(pp[2 * kh + 1][2]), "v"(pp[2 * kh + 1][3]));
    }

    // ---- PV ----
    __builtin_amdgcn_s_setprio(1);
#pragma unroll
    for (int kh = 0; kh < 2; ++kh)
#pragma unroll
      for (int db = 0; db < 4; ++db) {
        bf16x8 vf = *(const bf16x8*)&Vlds[cur][
            (db * 16 + lr) * 64 + ((4 * kh + lg) ^ (lr & 7)) * 8];
        ov[db] = __builtin_amdgcn_mfma_f32_16x16x32_bf16(
            pk[kh].v, vf, ov[db], 0, 0, 0);
      }
    __builtin_amdgcn_s_setprio(0);
  }

  // ---- epilogue ----
  float lsum = lpart;
  lsum += __shfl_xor(lsum, 16);
  lsum += __shfl_xor(lsum, 32);
  float invl = 1.0f / lsum;
#pragma unroll
  for (int r = 0; r < 4; ++r) {
    float iv = __shfl(invl, (lane & 48) | (lg * 4 + r));
    size_t row = (size_t)(bb * S_ + qw + lg * 4 + r);
#pragma unroll
    for (int db = 0; db < 4; ++db)
      ctxb[row * 1024 + h * 64 + db * 16 + lr] = f2bf(ov[db][r] * iv);
  }
}

extern "C" void kernel_launch(void* const* d_in, const int* in_sizes, int n_in,
                              void* d_out, int out_size, void* d_ws, size_t ws_size,
                              hipStream_t stream) {
  const float* hs      = (const float*)d_in[0];
  const float* w_qkv   = (const float*)d_in[1];
  const float* b_qkv   = (const float*)d_in[2];
  const float* w_dense = (const float*)d_in[3];
  const float* b_dense = (const float*)d_in[4];
  const float* rtab    = (const float*)d_in[5];
  float* out = (float*)d_out;

  char* ws = (char*)d_ws;
  unsigned short* qkvb = (unsigned short*)ws;                          // 24 MB
  unsigned short* ctxb = (unsigned short*)(ws + (((size_t)24) << 20)); // 8 MB
  unsigned short* hsb  = (unsigned short*)(ws + (((size_t)32) << 20)); // 8 MB
  unsigned short* wqT  = (unsigned short*)(ws + (((size_t)40) << 20)); // 6 MB
  unsigned short* wdT  = (unsigned short*)(ws + (((size_t)46) << 20)); // 2 MB
  unsigned short* vP   = (unsigned short*)(ws + (((size_t)48) << 20)); // 8 MB
  float* biasTab       = (float*)(ws + (((size_t)56) << 20));          // 256 KB

  hipLaunchKernelGGL(prologue_kernel, dim3(3328), dim3(256), 0, stream,
                     hs, hsb, w_qkv, wqT, w_dense, wdT, rtab, biasTab);
  hipLaunchKernelGGL((gemm_mfma_kernel<true>), dim3(24, 32), dim3(256), 0, stream,
                     hsb, wqT, b_qkv, (void*)qkvb, 4096, 3072, 1024);
  hipLaunchKernelGGL(vperm_kernel, dim3(32, 16, 2), dim3(256), 0, stream,
                     qkvb, vP);
  hipLaunchKernelGGL(attn_mfma6_kernel, dim3(512), dim3(512), 0, stream,
                     qkvb, vP, biasTab, ctxb);
  hipLaunchKernelGGL((gemm_mfma64_kernel<false>), dim3(8, 64), dim3(256), 0, stream,
                     ctxb, wdT, b_dense, (void*)out, 4096, 1024, 1024);
}

// Round 13
// 131.553 us; speedup vs baseline: 1.2522x; 1.0194x over previous
//
#include <hip/hip_runtime.h>
#include <hip/hip_bf16.h>
#include <math.h>

#define S_ 2048

typedef __attribute__((ext_vector_type(8))) short bf16x8;
typedef __attribute__((ext_vector_type(4))) float f32x4;
typedef __attribute__((ext_vector_type(8))) unsigned short u16x8;
typedef __attribute__((ext_vector_type(4))) unsigned short u16x4;

__device__ inline unsigned short f2bf(float f) {
  union { float f; unsigned u; } x; x.f = f;
  unsigned r = x.u + 0x7fff + ((x.u >> 16) & 1);
  return (unsigned short)(r >> 16);
}

__device__ __forceinline__ float exp2_raw(float x) {
  float r;
  asm("v_exp_f32 %0, %1" : "=v"(r) : "v"(x));
  return r;
}

__device__ __forceinline__ void gll16(const unsigned short* g, unsigned short* l) {
  __builtin_amdgcn_global_load_lds(
      (const __attribute__((address_space(1))) unsigned int*)g,
      (__attribute__((address_space(3))) unsigned int*)l, 16, 0, 0);
}

// ---------------- fused prologue ----------------
__device__ __forceinline__ void transpose_tile(
    const float* __restrict__ in, unsigned short* __restrict__ out,
    int K, int N, int bx, int by, int tid, unsigned short (*tile)[72]) {
  const int k0 = by * 64, n0 = bx * 64;
  const int rr = tid >> 4, cc = (tid & 15) * 4;
#pragma unroll
  for (int p = 0; p < 4; ++p) {
    int k = rr + p * 16;
    float4 v = *(const float4*)&in[(size_t)(k0 + k) * N + n0 + cc];
    tile[k][cc + 0] = f2bf(v.x);
    tile[k][cc + 1] = f2bf(v.y);
    tile[k][cc + 2] = f2bf(v.z);
    tile[k][cc + 3] = f2bf(v.w);
  }
  __syncthreads();
#pragma unroll
  for (int p = 0; p < 4; ++p) {
    int n = rr + p * 16;
    u16x4 o;
    o[0] = tile[cc + 0][n];
    o[1] = tile[cc + 1][n];
    o[2] = tile[cc + 2][n];
    o[3] = tile[cc + 3][n];
    *(u16x4*)&out[(size_t)(n0 + n) * K + k0 + cc] = o;
  }
}

__global__ __launch_bounds__(256) void prologue_kernel(
    const float* __restrict__ hs, unsigned short* __restrict__ hsb,
    const float* __restrict__ w_qkv, unsigned short* __restrict__ wqT,
    const float* __restrict__ w_dense, unsigned short* __restrict__ wdT,
    const float* __restrict__ table, float* __restrict__ biasTab) {
  __shared__ unsigned short tile[64][72];
  const int blk = blockIdx.x;
  const int tid = threadIdx.x;
  if (blk < 2048) {
    int i = blk * 256 + tid;
    float4 a = ((const float4*)hs)[i * 2];
    float4 b = ((const float4*)hs)[i * 2 + 1];
    u16x8 o;
    o[0] = f2bf(a.x); o[1] = f2bf(a.y); o[2] = f2bf(a.z); o[3] = f2bf(a.w);
    o[4] = f2bf(b.x); o[5] = f2bf(b.y); o[6] = f2bf(b.z); o[7] = f2bf(b.w);
    *(u16x8*)&hsb[(size_t)i * 8] = o;
  } else if (blk < 2816) {
    int t = blk - 2048;
    transpose_tile(w_qkv, wqT, 1024, 3072, t % 48, t / 48, tid, tile);
  } else if (blk < 3072) {
    int t = blk - 2816;
    transpose_tile(w_dense, wdT, 1024, 1024, t % 16, t / 16, tid, tile);
  } else {
    int idx = (blk - 3072) * 256 + tid;
    int h = idx >> 12;
    int r = idx & 4095;
    int rel = r - 2047;
    int bucket = rel > 0 ? 16 : 0;
    int ar = rel < 0 ? -rel : rel;
    if (ar < 8) {
      bucket += ar;
    } else {
      float tmp = logf((float)ar / 8.0f);
      float lf = tmp / 2.7725887222397811f * 8.0f;
      int large = 8 + (int)lf;
      bucket += (large < 15 ? large : 15);
    }
    biasTab[idx] = table[h * 32 + bucket] * 1.44269504088896f;  // log2e domain
  }
}

// ------- bf16 MFMA GEMM, 128x128 tile: C = A @ Bt^T + bias (XCD-swizzled) ----
// BF16OUT epilogue: per-wave LDS repack -> coalesced u16x8 stores.
template <bool BF16OUT>
__global__ __launch_bounds__(256) void gemm_mfma_kernel(
    const unsigned short* __restrict__ A, const unsigned short* __restrict__ Bt,
    const float* __restrict__ bias, void* __restrict__ Cout,
    int M, int N, int K) {
  __shared__ __align__(16) unsigned short As[128 * 32];
  __shared__ __align__(16) unsigned short Bs[128 * 32];
  const int tid = threadIdx.x;
  const int wave = tid >> 6, lane = tid & 63;
  const int lg = lane >> 4, lr = lane & 15;
  const int nbx = gridDim.x;
  const int flat = blockIdx.y * nbx + blockIdx.x;
  const int cpx = (nbx * gridDim.y) >> 3;
  const int swzid = (flat & 7) * cpx + (flat >> 3);
  const int m0 = (swzid / nbx) * 128, n0 = (swzid % nbx) * 128;
  const int wm = (wave & 1) * 64, wn = (wave >> 1) * 64;

  f32x4 acc[4][4] = {};

  const int r0 = tid >> 2;
  const int sw = ((tid & 3) ^ (r0 & 3)) << 3;
  const unsigned short* aP0 = A + (size_t)(m0 + r0) * K + sw;
  const unsigned short* aP1 = A + (size_t)(m0 + 64 + r0) * K + sw;
  const unsigned short* bP0 = Bt + (size_t)(n0 + r0) * K + sw;
  const unsigned short* bP1 = Bt + (size_t)(n0 + 64 + r0) * K + sw;
  unsigned short* ldsA0 = &As[(tid & ~63) * 8];
  unsigned short* ldsA1 = &As[(256 + (tid & ~63)) * 8];
  unsigned short* ldsB0 = &Bs[(tid & ~63) * 8];
  unsigned short* ldsB1 = &Bs[(256 + (tid & ~63)) * 8];

  const int swz = (lg ^ (lr & 3)) << 3;

  for (int kt = 0; kt < K; kt += 32) {
    __syncthreads();
    gll16(aP0 + kt, ldsA0);
    gll16(aP1 + kt, ldsA1);
    gll16(bP0 + kt, ldsB0);
    gll16(bP1 + kt, ldsB1);
    __syncthreads();
    bf16x8 af[4], bfr[4];
#pragma unroll
    for (int t = 0; t < 4; ++t) {
      af[t]  = *(const bf16x8*)&As[(wm + t * 16 + lr) * 32 + swz];
      bfr[t] = *(const bf16x8*)&Bs[(wn + t * 16 + lr) * 32 + swz];
    }
#pragma unroll
    for (int i = 0; i < 4; ++i)
#pragma unroll
      for (int j = 0; j < 4; ++j)
        acc[i][j] = __builtin_amdgcn_mfma_f32_16x16x32_bf16(
            af[i], bfr[j], acc[i][j], 0, 0, 0);
  }

  float bv[4];
#pragma unroll
  for (int j = 0; j < 4; ++j) bv[j] = bias[n0 + wn + j * 16 + lr];

  if constexpr (BF16OUT) {
    // per-wave repack region: 16 rows x 64 cols bf16 = 2 KB in As[wave*1024..]
    __syncthreads();   // main-loop frag reads of As complete before overwrite
    unsigned short* rp = &As[wave * 1024];
#pragma unroll
    for (int i = 0; i < 4; ++i) {
#pragma unroll
      for (int j = 0; j < 4; ++j) {
        const int cw = ((j + lg) & 3) * 16 + lr;   // j-rotated col (2-way banks)
#pragma unroll
        for (int r = 0; r < 4; ++r)
          rp[(lg * 4 + r) * 64 + cw] = f2bf(acc[i][j][r] + bv[j]);
      }
      // read back coalesced (same wave; lgkm ordering suffices)
#pragma unroll
      for (int pass = 0; pass < 2; ++pass) {
        const int row = pass * 8 + (lane >> 3);
        const int cread = ((((lane & 7) >> 1) + (row >> 2)) & 3) * 16 +
                          (lane & 1) * 8;
        u16x8 v = *(const u16x8*)&rp[row * 64 + cread];
        *(u16x8*)&((unsigned short*)Cout)[
            (size_t)(m0 + wm + i * 16 + row) * N + n0 + wn + (lane & 7) * 8] = v;
      }
    }
  } else {
#pragma unroll
    for (int i = 0; i < 4; ++i)
#pragma unroll
      for (int j = 0; j < 4; ++j)
#pragma unroll
        for (int r = 0; r < 4; ++r) {
          int row = m0 + wm + i * 16 + lg * 4 + r;
          int col = n0 + wn + j * 16 + lr;
          ((float*)Cout)[(size_t)row * N + col] = acc[i][j][r] + bv[j];
        }
  }
}

// ------- bf16 MFMA GEMM, 64x128 tile (2x occupancy for small-grid shapes) ----
template <bool BF16OUT>
__global__ __launch_bounds__(256) void gemm_mfma64_kernel(
    const unsigned short* __restrict__ A, const unsigned short* __restrict__ Bt,
    const float* __restrict__ bias, void* __restrict__ Cout,
    int M, int N, int K) {
  __shared__ __align__(16) unsigned short As[64 * 32];
  __shared__ __align__(16) unsigned short Bs[128 * 32];
  const int tid = threadIdx.x;
  const int wave = tid >> 6, lane = tid & 63;
  const int lg = lane >> 4, lr = lane & 15;
  const int nbx = gridDim.x;
  const int flat = blockIdx.y * nbx + blockIdx.x;
  const int cpx = (nbx * gridDim.y) >> 3;
  const int swzid = (flat & 7) * cpx + (flat >> 3);
  const int m0 = (swzid / nbx) * 64, n0 = (swzid % nbx) * 128;
  const int wm = (wave & 1) * 32, wn = (wave >> 1) * 64;

  f32x4 acc[2][4] = {};

  const int r0 = tid >> 2;
  const int sw = ((tid & 3) ^ (r0 & 3)) << 3;
  const unsigned short* aP  = A + (size_t)(m0 + r0) * K + sw;
  const unsigned short* bP0 = Bt + (size_t)(n0 + r0) * K + sw;
  const unsigned short* bP1 = Bt + (size_t)(n0 + 64 + r0) * K + sw;
  unsigned short* ldsA  = &As[(tid & ~63) * 8];
  unsigned short* ldsB0 = &Bs[(tid & ~63) * 8];
  unsigned short* ldsB1 = &Bs[(256 + (tid & ~63)) * 8];

  const int swz = (lg ^ (lr & 3)) << 3;

  for (int kt = 0; kt < K; kt += 32) {
    __syncthreads();
    gll16(aP + kt, ldsA);
    gll16(bP0 + kt, ldsB0);
    gll16(bP1 + kt, ldsB1);
    __syncthreads();
    bf16x8 af[2], bfr[4];
#pragma unroll
    for (int t = 0; t < 2; ++t)
      af[t] = *(const bf16x8*)&As[(wm + t * 16 + lr) * 32 + swz];
#pragma unroll
    for (int t = 0; t < 4; ++t)
      bfr[t] = *(const bf16x8*)&Bs[(wn + t * 16 + lr) * 32 + swz];
#pragma unroll
    for (int i = 0; i < 2; ++i)
#pragma unroll
      for (int j = 0; j < 4; ++j)
        acc[i][j] = __builtin_amdgcn_mfma_f32_16x16x32_bf16(
            af[i], bfr[j], acc[i][j], 0, 0, 0);
  }

  float bv[4];
#pragma unroll
  for (int j = 0; j < 4; ++j) bv[j] = bias[n0 + wn + j * 16 + lr];
#pragma unroll
  for (int i = 0; i < 2; ++i) {
#pragma unroll
    for (int j = 0; j < 4; ++j) {
#pragma unroll
      for (int r = 0; r < 4; ++r) {
        int row = m0 + wm + i * 16 + lg * 4 + r;
        int col = n0 + wn + j * 16 + lr;
        float val = acc[i][j][r] + bv[j];
        if constexpr (BF16OUT)
          ((unsigned short*)Cout)[(size_t)row * N + col] = f2bf(val);
        else
          ((float*)Cout)[(size_t)row * N + col] = val;
      }
    }
  }
}

// ---------------- V permute pre-pass (16x16 kappa order) ----------------
__global__ __launch_bounds__(256) void vperm_kernel(
    const unsigned short* __restrict__ qkvb, unsigned short* __restrict__ vP) {
  const int t = blockIdx.x, h = blockIdx.y, bb = blockIdx.z;
  __shared__ unsigned short tile[64][72];
  const int tid = threadIdx.x;
  {
    int k = tid >> 2, c = (tid & 3) * 16;
    const unsigned short* src =
        qkvb + (size_t)(bb * S_ + t * 64 + k) * 3072 + 2048 + h * 64 + c;
    *(bf16x8*)&tile[k][c] = *(const bf16x8*)src;
    *(bf16x8*)&tile[k][c + 8] = *(const bf16x8*)(src + 8);
  }
  __syncthreads();
  const int d = tid >> 2, m0 = (tid & 3) * 16;
  unsigned short* dst =
      vP + ((size_t)((bb * 16 + h) * 64 + d)) * S_ + t * 64 + m0;
#pragma unroll
  for (int half = 0; half < 2; ++half) {
    u16x8 o;
#pragma unroll
    for (int j = 0; j < 8; ++j) {
      int m = m0 + half * 8 + j;
      int phys_s = m >> 3, e = m & 7;
      int s = phys_s ^ (d & 7);
      int w = s >> 2, lg = s & 3;
      int kw = w * 32 + (e >> 2) * 16 + lg * 4 + (e & 3);
      o[j] = tile[kw][d];
    }
    *(u16x8*)(dst + half * 8) = o;
  }
}

// ---------------- bf16 MFMA flash attention v6 (+ V-frag hoist) ----------------
__global__ __launch_bounds__(512) void attn_mfma6_kernel(
    const unsigned short* __restrict__ qkvb, const unsigned short* __restrict__ vP,
    const float* __restrict__ biasTab, unsigned short* __restrict__ ctxb) {
  const int wg0 = blockIdx.x;
  const int wg = (wg0 & 7) * 64 + (wg0 >> 3);
  const int qt = wg & 15;
  const int h  = (wg >> 4) & 15;
  const int bb = wg >> 8;

  const int tid = threadIdx.x;
  const int wave = tid >> 6;
  const int lane = tid & 63;
  const int lg = lane >> 4;
  const int lr = lane & 15;

  __shared__ __align__(16) unsigned short Klds[2][4096];
  __shared__ __align__(16) unsigned short Vlds[2][4096];
  __shared__ float biasW[2][192];

  const int q0 = qt * 128;
  const int qw = q0 + wave * 16;
  const float SCL = 0.125f * 1.44269504088896f;
  const float THR = 11.5415603f;

  bf16x8 qf[2];
#pragma unroll
  for (int kh = 0; kh < 2; ++kh)
    qf[kh] = *(const bf16x8*)(qkvb +
        (size_t)(bb * S_ + qw + lr) * 3072 + h * 64 + kh * 32 + lg * 8);

  float mrun = -1e30f;
  float lpart = 0.f;
  f32x4 ov[4] = {};

  const int kk = tid >> 3, kpb = tid & 7;
  const unsigned short* kptr = qkvb + (size_t)(bb * S_ + kk) * 3072 + 1024 +
                               h * 64 + (kpb ^ (kk & 7)) * 8;
  const unsigned short* vptr = vP + ((size_t)((bb * 16 + h) * 64 + (tid >> 3))) * S_ +
                               (tid & 7) * 8;
  const float* btabH = biasTab + h * 4096 + 2047;

  auto nonuni = [&](int tt) {
    int rl = tt * 64 - q0;
    return !((rl - 127 >= 91) || (rl + 63 <= -91));
  };

  gll16(kptr, &Klds[0][(tid & ~63) * 8]);
  gll16(vptr, &Vlds[0][(tid & ~63) * 8]);
  if (nonuni(0) && tid < 192) biasW[0][tid] = btabH[-q0 - 127 + tid];

  for (int t = 0; t < 32; ++t) {
    const int cur = t & 1;
    __syncthreads();

    if (t < 31) {
      const size_t kadv = (size_t)(t + 1) * 64 * 3072;
      gll16(kptr + kadv, &Klds[cur ^ 1][(tid & ~63) * 8]);
      gll16(vptr + (t + 1) * 64, &Vlds[cur ^ 1][(tid & ~63) * 8]);
      if (nonuni(t + 1) && tid < 192)
        biasW[cur ^ 1][tid] = btabH[(t + 1) * 64 - q0 - 127 + tid];
    }

    // ---- QK^T swapped ----
    f32x4 sc[4] = {};
    __builtin_amdgcn_s_setprio(1);
#pragma unroll
    for (int kt = 0; kt < 4; ++kt) {
      const unsigned short* kr = &Klds[cur][(kt * 16 + lr) * 64];
      bf16x8 kf0 = *(const bf16x8*)(kr + ((lg)     ^ (lr & 7)) * 8);
      bf16x8 kf1 = *(const bf16x8*)(kr + ((4 + lg) ^ (lr & 7)) * 8);
      sc[kt] = __builtin_amdgcn_mfma_f32_16x16x32_bf16(kf0, qf[0], sc[kt], 0, 0, 0);
      sc[kt] = __builtin_amdgcn_mfma_f32_16x16x32_bf16(kf1, qf[1], sc[kt], 0, 0, 0);
    }
    __builtin_amdgcn_s_setprio(0);

    // ---- V fragments hoisted: overlap LDS reads with softmax VALU ----
    bf16x8 vfr[2][4];
#pragma unroll
    for (int kh = 0; kh < 2; ++kh)
#pragma unroll
      for (int db = 0; db < 4; ++db)
        vfr[kh][db] = *(const bf16x8*)&Vlds[cur][
            (db * 16 + lr) * 64 + ((4 * kh + lg) ^ (lr & 7)) * 8];

    // ---- bias (log2e domain) ----
    float pp[4][4];
    if (nonuni(t)) {
      const int bidx = 127 + lg * 4 - wave * 16 - lr;
#pragma unroll
      for (int kt = 0; kt < 4; ++kt)
#pragma unroll
        for (int r = 0; r < 4; ++r)
          pp[kt][r] = sc[kt][r] * SCL + biasW[cur][bidx + kt * 16 + r];
    } else {
      const float cb = btabH[t * 64 - q0];
#pragma unroll
      for (int kt = 0; kt < 4; ++kt)
#pragma unroll
        for (int r = 0; r < 4; ++r)
          pp[kt][r] = sc[kt][r] * SCL + cb;
    }

    // ---- lane-local max (tree) ----
    float mx[8];
#pragma unroll
    for (int i = 0; i < 8; ++i)
      mx[i] = fmaxf(pp[i >> 1][(i & 1) * 2], pp[i >> 1][(i & 1) * 2 + 1]);
    float m01 = fmaxf(mx[0], mx[1]), m23 = fmaxf(mx[2], mx[3]);
    float m45 = fmaxf(mx[4], mx[5]), m67 = fmaxf(mx[6], mx[7]);
    float tm = fmaxf(fmaxf(m01, m23), fmaxf(m45, m67));

    // ---- lazy row-max ----
    if (!__all(tm <= mrun + THR)) {
      tm = fmaxf(tm, __shfl_xor(tm, 16));
      tm = fmaxf(tm, __shfl_xor(tm, 32));
      float mn = fmaxf(mrun, tm);
      float sfv = exp2_raw(mrun - mn);
      mrun = mn;
      lpart *= sfv;
#pragma unroll
      for (int r = 0; r < 4; ++r) {
        float sq = __shfl(sfv, (lane & 48) | (lg * 4 + r));
#pragma unroll
        for (int db = 0; db < 4; ++db) ov[db][r] *= sq;
      }
    }

    // ---- exp2 + per-lane partial sum ----
#pragma unroll
    for (int kt = 0; kt < 4; ++kt)
#pragma unroll
      for (int r = 0; r < 4; ++r)
        pp[kt][r] = exp2_raw(pp[kt][r] - mrun);
    float s8[8];
#pragma unroll
    for (int i = 0; i < 8; ++i)
      s8[i] = pp[i >> 1][(i & 1) * 2] + pp[i >> 1][(i & 1) * 2 + 1];
    float s01 = s8[0] + s8[1], s23 = s8[2] + s8[3];
    float s45 = s8[4] + s8[5], s67 = s8[6] + s8[7];
    lpart += (s01 + s23) + (s45 + s67);

    // ---- pack P via v_cvt_pk_bf16_f32 ----
    union { bf16x8 v; unsigned u[4]; } pk[2];
#pragma unroll
    for (int kh = 0; kh < 2; ++kh) {
      asm("v_cvt_pk_bf16_f32 %0, %1, %2"
          : "=v"(pk[kh].u[0]) : "v"(pp[2 * kh][0]), "v"(pp[2 * kh][1]));
      asm("v_cvt_pk_bf16_f32 %0, %1, %2"
          : "=v"(pk[kh].u[1]) : "v"(pp[2 * kh][2]), "v"(pp[2 * kh][3]));
      asm("v_cvt_pk_bf16_f32 %0, %1, %2"
          : "=v"(pk[kh].u[2]) : "v"(pp[2 * kh + 1][0]), "v"(pp[2 * kh + 1][1]));
      asm("v_cvt_pk_bf16_f32 %0, %1, %2"
          : "=v"(pk[kh].u[3]) : "v"(pp[2 * kh + 1][2]), "v"(pp[2 * kh + 1][3]));
    }

    // ---- PV ----
    __builtin_amdgcn_s_setprio(1);
#pragma unroll
    for (int kh = 0; kh < 2; ++kh)
#pragma unroll
      for (int db = 0; db < 4; ++db)
        ov[db] = __builtin_amdgcn_mfma_f32_16x16x32_bf16(
            pk[kh].v, vfr[kh][db], ov[db], 0, 0, 0);
    __builtin_amdgcn_s_setprio(0);
  }

  // ---- epilogue ----
  float lsum = lpart;
  lsum += __shfl_xor(lsum, 16);
  lsum += __shfl_xor(lsum, 32);
  float invl = 1.0f / lsum;
#pragma unroll
  for (int r = 0; r < 4; ++r) {
    float iv = __shfl(invl, (lane & 48) | (lg * 4 + r));
    size_t row = (size_t)(bb * S_ + qw + lg * 4 + r);
#pragma unroll
    for (int db = 0; db < 4; ++db)
      ctxb[row * 1024 + h * 64 + db * 16 + lr] = f2bf(ov[db][r] * iv);
  }
}

extern "C" void kernel_launch(void* const* d_in, const int* in_sizes, int n_in,
                              void* d_out, int out_size, void* d_ws, size_t ws_size,
                              hipStream_t stream) {
  const float* hs      = (const float*)d_in[0];
  const float* w_qkv   = (const float*)d_in[1];
  const float* b_qkv   = (const float*)d_in[2];
  const float* w_dense = (const float*)d_in[3];
  const float* b_dense = (const float*)d_in[4];
  const float* rtab    = (const float*)d_in[5];
  float* out = (float*)d_out;

  char* ws = (char*)d_ws;
  unsigned short* qkvb = (unsigned short*)ws;                          // 24 MB
  unsigned short* ctxb = (unsigned short*)(ws + (((size_t)24) << 20)); // 8 MB
  unsigned short* hsb  = (unsigned short*)(ws + (((size_t)32) << 20)); // 8 MB
  unsigned short* wqT  = (unsigned short*)(ws + (((size_t)40) << 20)); // 6 MB
  unsigned short* wdT  = (unsigned short*)(ws + (((size_t)46) << 20)); // 2 MB
  unsigned short* vP   = (unsigned short*)(ws + (((size_t)48) << 20)); // 8 MB
  float* biasTab       = (float*)(ws + (((size_t)56) << 20));          // 256 KB

  hipLaunchKernelGGL(prologue_kernel, dim3(3328), dim3(256), 0, stream,
                     hs, hsb, w_qkv, wqT, w_dense, wdT, rtab, biasTab);
  hipLaunchKernelGGL((gemm_mfma_kernel<true>), dim3(24, 32), dim3(256), 0, stream,
                     hsb, wqT, b_qkv, (void*)qkvb, 4096, 3072, 1024);
  hipLaunchKernelGGL(vperm_kernel, dim3(32, 16, 2), dim3(256), 0, stream,
                     qkvb, vP);
  hipLaunchKernelGGL(attn_mfma6_kernel, dim3(512), dim3(512), 0, stream,
                     qkvb, vP, biasTab, ctxb);
  hipLaunchKernelGGL((gemm_mfma64_kernel<false>), dim3(8, 64), dim3(256), 0, stream,
                     ctxb, wdT, b_dense, (void*)out, 4096, 1024, 1024);
}

// Round 14
// 129.010 us; speedup vs baseline: 1.2769x; 1.0197x over previous
//
#include <hip/hip_runtime.h>
#include <hip/hip_bf16.h>
#include <math.h>

#define S_ 2048

typedef __attribute__((ext_vector_type(8))) short bf16x8;
typedef __attribute__((ext_vector_type(4))) float f32x4;
typedef __attribute__((ext_vector_type(8))) unsigned short u16x8;
typedef __attribute__((ext_vector_type(4))) unsigned short u16x4;

__device__ inline unsigned short f2bf(float f) {
  union { float f; unsigned u; } x; x.f = f;
  unsigned r = x.u + 0x7fff + ((x.u >> 16) & 1);
  return (unsigned short)(r >> 16);
}

__device__ __forceinline__ float exp2_raw(float x) {
  float r;
  asm("v_exp_f32 %0, %1" : "=v"(r) : "v"(x));
  return r;
}

__device__ __forceinline__ void gll16(const unsigned short* g, unsigned short* l) {
  __builtin_amdgcn_global_load_lds(
      (const __attribute__((address_space(1))) unsigned int*)g,
      (__attribute__((address_space(3))) unsigned int*)l, 16, 0, 0);
}

// ---------------- fused prologue ----------------
__device__ __forceinline__ void transpose_tile(
    const float* __restrict__ in, unsigned short* __restrict__ out,
    int K, int N, int bx, int by, int tid, unsigned short (*tile)[72]) {
  const int k0 = by * 64, n0 = bx * 64;
  const int rr = tid >> 4, cc = (tid & 15) * 4;
#pragma unroll
  for (int p = 0; p < 4; ++p) {
    int k = rr + p * 16;
    float4 v = *(const float4*)&in[(size_t)(k0 + k) * N + n0 + cc];
    tile[k][cc + 0] = f2bf(v.x);
    tile[k][cc + 1] = f2bf(v.y);
    tile[k][cc + 2] = f2bf(v.z);
    tile[k][cc + 3] = f2bf(v.w);
  }
  __syncthreads();
#pragma unroll
  for (int p = 0; p < 4; ++p) {
    int n = rr + p * 16;
    u16x4 o;
    o[0] = tile[cc + 0][n];
    o[1] = tile[cc + 1][n];
    o[2] = tile[cc + 2][n];
    o[3] = tile[cc + 3][n];
    *(u16x4*)&out[(size_t)(n0 + n) * K + k0 + cc] = o;
  }
}

__global__ __launch_bounds__(256) void prologue_kernel(
    const float* __restrict__ hs, unsigned short* __restrict__ hsb,
    const float* __restrict__ w_qkv, unsigned short* __restrict__ wqT,
    const float* __restrict__ w_dense, unsigned short* __restrict__ wdT,
    const float* __restrict__ table, float* __restrict__ biasTab) {
  __shared__ unsigned short tile[64][72];
  const int blk = blockIdx.x;
  const int tid = threadIdx.x;
  if (blk < 2048) {
    int i = blk * 256 + tid;
    float4 a = ((const float4*)hs)[i * 2];
    float4 b = ((const float4*)hs)[i * 2 + 1];
    u16x8 o;
    o[0] = f2bf(a.x); o[1] = f2bf(a.y); o[2] = f2bf(a.z); o[3] = f2bf(a.w);
    o[4] = f2bf(b.x); o[5] = f2bf(b.y); o[6] = f2bf(b.z); o[7] = f2bf(b.w);
    *(u16x8*)&hsb[(size_t)i * 8] = o;
  } else if (blk < 2816) {
    int t = blk - 2048;
    transpose_tile(w_qkv, wqT, 1024, 3072, t % 48, t / 48, tid, tile);
  } else if (blk < 3072) {
    int t = blk - 2816;
    transpose_tile(w_dense, wdT, 1024, 1024, t % 16, t / 16, tid, tile);
  } else {
    int idx = (blk - 3072) * 256 + tid;
    int h = idx >> 12;
    int r = idx & 4095;
    int rel = r - 2047;
    int bucket = rel > 0 ? 16 : 0;
    int ar = rel < 0 ? -rel : rel;
    if (ar < 8) {
      bucket += ar;
    } else {
      float tmp = logf((float)ar / 8.0f);
      float lf = tmp / 2.7725887222397811f * 8.0f;
      int large = 8 + (int)lf;
      bucket += (large < 15 ? large : 15);
    }
    biasTab[idx] = table[h * 32 + bucket] * 1.44269504088896f;  // log2e domain
  }
}

// ------- bf16 MFMA GEMM, 128x128 tile, BK=64: C = A @ Bt^T + bias ------------
// XCD-swizzled; BF16OUT epilogue: per-wave LDS repack -> coalesced u16x8 stores.
template <bool BF16OUT>
__global__ __launch_bounds__(256) void gemm_mfma_kernel(
    const unsigned short* __restrict__ A, const unsigned short* __restrict__ Bt,
    const float* __restrict__ bias, void* __restrict__ Cout,
    int M, int N, int K) {
  __shared__ __align__(16) unsigned short As[128 * 64];
  __shared__ __align__(16) unsigned short Bs[128 * 64];
  const int tid = threadIdx.x;
  const int wave = tid >> 6, lane = tid & 63;
  const int lg = lane >> 4, lr = lane & 15;
  const int nbx = gridDim.x;
  const int flat = blockIdx.y * nbx + blockIdx.x;
  const int cpx = (nbx * gridDim.y) >> 3;
  const int swzid = (flat & 7) * cpx + (flat >> 3);
  const int m0 = (swzid / nbx) * 128, n0 = (swzid % nbx) * 128;
  const int wm = (wave & 1) * 64, wn = (wave >> 1) * 64;

  f32x4 acc[4][4] = {};

  // staging: chunk c = g*256 + tid -> row = g*32 + (tid>>3), slot = tid&7,
  // source col-slot ls = (tid&7) ^ ((tid>>3)&7)  (row&7 == (tid>>3)&7)
  const int rbase = tid >> 3;
  const int lsw = ((tid & 7) ^ (rbase & 7)) * 8;
  const unsigned short* aP[4];
  const unsigned short* bP[4];
  unsigned short* ldsA[4];
  unsigned short* ldsB[4];
#pragma unroll
  for (int g = 0; g < 4; ++g) {
    aP[g] = A + (size_t)(m0 + g * 32 + rbase) * K + lsw;
    bP[g] = Bt + (size_t)(n0 + g * 32 + rbase) * K + lsw;
    ldsA[g] = &As[g * 2048 + (tid & ~63) * 8];
    ldsB[g] = &Bs[g * 2048 + (tid & ~63) * 8];
  }

  for (int kt = 0; kt < K; kt += 64) {
    __syncthreads();
#pragma unroll
    for (int g = 0; g < 4; ++g) {
      gll16(aP[g] + kt, ldsA[g]);
      gll16(bP[g] + kt, ldsB[g]);
    }
    __syncthreads();
#pragma unroll
    for (int kh = 0; kh < 2; ++kh) {
      bf16x8 af[4], bfr[4];
#pragma unroll
      for (int t = 0; t < 4; ++t) {
        const int slot = ((kh * 4 + lg) ^ (lr & 7)) * 8;
        af[t]  = *(const bf16x8*)&As[(wm + t * 16 + lr) * 64 + slot];
        bfr[t] = *(const bf16x8*)&Bs[(wn + t * 16 + lr) * 64 + slot];
      }
#pragma unroll
      for (int i = 0; i < 4; ++i)
#pragma unroll
        for (int j = 0; j < 4; ++j)
          acc[i][j] = __builtin_amdgcn_mfma_f32_16x16x32_bf16(
              af[i], bfr[j], acc[i][j], 0, 0, 0);
    }
  }

  float bv[4];
#pragma unroll
  for (int j = 0; j < 4; ++j) bv[j] = bias[n0 + wn + j * 16 + lr];

  if constexpr (BF16OUT) {
    __syncthreads();   // main-loop frag reads of As complete before overwrite
    unsigned short* rp = &As[wave * 1024];
#pragma unroll
    for (int i = 0; i < 4; ++i) {
#pragma unroll
      for (int j = 0; j < 4; ++j) {
        const int cw = ((j + lg) & 3) * 16 + lr;
#pragma unroll
        for (int r = 0; r < 4; ++r)
          rp[(lg * 4 + r) * 64 + cw] = f2bf(acc[i][j][r] + bv[j]);
      }
#pragma unroll
      for (int pass = 0; pass < 2; ++pass) {
        const int row = pass * 8 + (lane >> 3);
        const int cread = ((((lane & 7) >> 1) + (row >> 2)) & 3) * 16 +
                          (lane & 1) * 8;
        u16x8 v = *(const u16x8*)&rp[row * 64 + cread];
        *(u16x8*)&((unsigned short*)Cout)[
            (size_t)(m0 + wm + i * 16 + row) * N + n0 + wn + (lane & 7) * 8] = v;
      }
    }
  } else {
#pragma unroll
    for (int i = 0; i < 4; ++i)
#pragma unroll
      for (int j = 0; j < 4; ++j)
#pragma unroll
        for (int r = 0; r < 4; ++r) {
          int row = m0 + wm + i * 16 + lg * 4 + r;
          int col = n0 + wn + j * 16 + lr;
          ((float*)Cout)[(size_t)row * N + col] = acc[i][j][r] + bv[j];
        }
  }
}

// ------- bf16 MFMA GEMM, 64x128 tile, BK=64 (2x occupancy, small shapes) -----
template <bool BF16OUT>
__global__ __launch_bounds__(256) void gemm_mfma64_kernel(
    const unsigned short* __restrict__ A, const unsigned short* __restrict__ Bt,
    const float* __restrict__ bias, void* __restrict__ Cout,
    int M, int N, int K) {
  __shared__ __align__(16) unsigned short As[64 * 64];
  __shared__ __align__(16) unsigned short Bs[128 * 64];
  const int tid = threadIdx.x;
  const int wave = tid >> 6, lane = tid & 63;
  const int lg = lane >> 4, lr = lane & 15;
  const int nbx = gridDim.x;
  const int flat = blockIdx.y * nbx + blockIdx.x;
  const int cpx = (nbx * gridDim.y) >> 3;
  const int swzid = (flat & 7) * cpx + (flat >> 3);
  const int m0 = (swzid / nbx) * 64, n0 = (swzid % nbx) * 128;
  const int wm = (wave & 1) * 32, wn = (wave >> 1) * 64;

  f32x4 acc[2][4] = {};

  const int rbase = tid >> 3;
  const int lsw = ((tid & 7) ^ (rbase & 7)) * 8;
  const unsigned short* aP[2];
  const unsigned short* bP[4];
  unsigned short* ldsA[2];
  unsigned short* ldsB[4];
#pragma unroll
  for (int g = 0; g < 2; ++g) {
    aP[g] = A + (size_t)(m0 + g * 32 + rbase) * K + lsw;
    ldsA[g] = &As[g * 2048 + (tid & ~63) * 8];
  }
#pragma unroll
  for (int g = 0; g < 4; ++g) {
    bP[g] = Bt + (size_t)(n0 + g * 32 + rbase) * K + lsw;
    ldsB[g] = &Bs[g * 2048 + (tid & ~63) * 8];
  }

  for (int kt = 0; kt < K; kt += 64) {
    __syncthreads();
#pragma unroll
    for (int g = 0; g < 2; ++g) gll16(aP[g] + kt, ldsA[g]);
#pragma unroll
    for (int g = 0; g < 4; ++g) gll16(bP[g] + kt, ldsB[g]);
    __syncthreads();
#pragma unroll
    for (int kh = 0; kh < 2; ++kh) {
      bf16x8 af[2], bfr[4];
      const int slotb = ((kh * 4 + lg) ^ (lr & 7)) * 8;
#pragma unroll
      for (int t = 0; t < 2; ++t)
        af[t] = *(const bf16x8*)&As[(wm + t * 16 + lr) * 64 + slotb];
#pragma unroll
      for (int t = 0; t < 4; ++t)
        bfr[t] = *(const bf16x8*)&Bs[(wn + t * 16 + lr) * 64 + slotb];
#pragma unroll
      for (int i = 0; i < 2; ++i)
#pragma unroll
        for (int j = 0; j < 4; ++j)
          acc[i][j] = __builtin_amdgcn_mfma_f32_16x16x32_bf16(
              af[i], bfr[j], acc[i][j], 0, 0, 0);
    }
  }

  float bv[4];
#pragma unroll
  for (int j = 0; j < 4; ++j) bv[j] = bias[n0 + wn + j * 16 + lr];
#pragma unroll
  for (int i = 0; i < 2; ++i) {
#pragma unroll
    for (int j = 0; j < 4; ++j) {
#pragma unroll
      for (int r = 0; r < 4; ++r) {
        int row = m0 + wm + i * 16 + lg * 4 + r;
        int col = n0 + wn + j * 16 + lr;
        float val = acc[i][j][r] + bv[j];
        if constexpr (BF16OUT)
          ((unsigned short*)Cout)[(size_t)row * N + col] = f2bf(val);
        else
          ((float*)Cout)[(size_t)row * N + col] = val;
      }
    }
  }
}

// ---------------- V permute pre-pass (16x16 kappa order) ----------------
__global__ __launch_bounds__(256) void vperm_kernel(
    const unsigned short* __restrict__ qkvb, unsigned short* __restrict__ vP) {
  const int t = blockIdx.x, h = blockIdx.y, bb = blockIdx.z;
  __shared__ unsigned short tile[64][72];
  const int tid = threadIdx.x;
  {
    int k = tid >> 2, c = (tid & 3) * 16;
    const unsigned short* src =
        qkvb + (size_t)(bb * S_ + t * 64 + k) * 3072 + 2048 + h * 64 + c;
    *(bf16x8*)&tile[k][c] = *(const bf16x8*)src;
    *(bf16x8*)&tile[k][c + 8] = *(const bf16x8*)(src + 8);
  }
  __syncthreads();
  const int d = tid >> 2, m0 = (tid & 3) * 16;
  unsigned short* dst =
      vP + ((size_t)((bb * 16 + h) * 64 + d)) * S_ + t * 64 + m0;
#pragma unroll
  for (int half = 0; half < 2; ++half) {
    u16x8 o;
#pragma unroll
    for (int j = 0; j < 8; ++j) {
      int m = m0 + half * 8 + j;
      int phys_s = m >> 3, e = m & 7;
      int s = phys_s ^ (d & 7);
      int w = s >> 2, lg = s & 3;
      int kw = w * 32 + (e >> 2) * 16 + lg * 4 + (e & 3);
      o[j] = tile[kw][d];
    }
    *(u16x8*)(dst + half * 8) = o;
  }
}

// ---------------- bf16 MFMA flash attention v6 (+ V-frag hoist) ----------------
__global__ __launch_bounds__(512) void attn_mfma6_kernel(
    const unsigned short* __restrict__ qkvb, const unsigned short* __restrict__ vP,
    const float* __restrict__ biasTab, unsigned short* __restrict__ ctxb) {
  const int wg0 = blockIdx.x;
  const int wg = (wg0 & 7) * 64 + (wg0 >> 3);
  const int qt = wg & 15;
  const int h  = (wg >> 4) & 15;
  const int bb = wg >> 8;

  const int tid = threadIdx.x;
  const int wave = tid >> 6;
  const int lane = tid & 63;
  const int lg = lane >> 4;
  const int lr = lane & 15;

  __shared__ __align__(16) unsigned short Klds[2][4096];
  __shared__ __align__(16) unsigned short Vlds[2][4096];
  __shared__ float biasW[2][192];

  const int q0 = qt * 128;
  const int qw = q0 + wave * 16;
  const float SCL = 0.125f * 1.44269504088896f;
  const float THR = 11.5415603f;

  bf16x8 qf[2];
#pragma unroll
  for (int kh = 0; kh < 2; ++kh)
    qf[kh] = *(const bf16x8*)(qkvb +
        (size_t)(bb * S_ + qw + lr) * 3072 + h * 64 + kh * 32 + lg * 8);

  float mrun = -1e30f;
  float lpart = 0.f;
  f32x4 ov[4] = {};

  const int kk = tid >> 3, kpb = tid & 7;
  const unsigned short* kptr = qkvb + (size_t)(bb * S_ + kk) * 3072 + 1024 +
                               h * 64 + (kpb ^ (kk & 7)) * 8;
  const unsigned short* vptr = vP + ((size_t)((bb * 16 + h) * 64 + (tid >> 3))) * S_ +
                               (tid & 7) * 8;
  const float* btabH = biasTab + h * 4096 + 2047;

  auto nonuni = [&](int tt) {
    int rl = tt * 64 - q0;
    return !((rl - 127 >= 91) || (rl + 63 <= -91));
  };

  gll16(kptr, &Klds[0][(tid & ~63) * 8]);
  gll16(vptr, &Vlds[0][(tid & ~63) * 8]);
  if (nonuni(0) && tid < 192) biasW[0][tid] = btabH[-q0 - 127 + tid];

  for (int t = 0; t < 32; ++t) {
    const int cur = t & 1;
    __syncthreads();

    if (t < 31) {
      const size_t kadv = (size_t)(t + 1) * 64 * 3072;
      gll16(kptr + kadv, &Klds[cur ^ 1][(tid & ~63) * 8]);
      gll16(vptr + (t + 1) * 64, &Vlds[cur ^ 1][(tid & ~63) * 8]);
      if (nonuni(t + 1) && tid < 192)
        biasW[cur ^ 1][tid] = btabH[(t + 1) * 64 - q0 - 127 + tid];
    }

    // ---- QK^T swapped ----
    f32x4 sc[4] = {};
    __builtin_amdgcn_s_setprio(1);
#pragma unroll
    for (int kt = 0; kt < 4; ++kt) {
      const unsigned short* kr = &Klds[cur][(kt * 16 + lr) * 64];
      bf16x8 kf0 = *(const bf16x8*)(kr + ((lg)     ^ (lr & 7)) * 8);
      bf16x8 kf1 = *(const bf16x8*)(kr + ((4 + lg) ^ (lr & 7)) * 8);
      sc[kt] = __builtin_amdgcn_mfma_f32_16x16x32_bf16(kf0, qf[0], sc[kt], 0, 0, 0);
      sc[kt] = __builtin_amdgcn_mfma_f32_16x16x32_bf16(kf1, qf[1], sc[kt], 0, 0, 0);
    }
    __builtin_amdgcn_s_setprio(0);

    // ---- V fragments hoisted ----
    bf16x8 vfr[2][4];
#pragma unroll
    for (int kh = 0; kh < 2; ++kh)
#pragma unroll
      for (int db = 0; db < 4; ++db)
        vfr[kh][db] = *(const bf16x8*)&Vlds[cur][
            (db * 16 + lr) * 64 + ((4 * kh + lg) ^ (lr & 7)) * 8];

    // ---- bias (log2e domain) ----
    float pp[4][4];
    if (nonuni(t)) {
      const int bidx = 127 + lg * 4 - wave * 16 - lr;
#pragma unroll
      for (int kt = 0; kt < 4; ++kt)
#pragma unroll
        for (int r = 0; r < 4; ++r)
          pp[kt][r] = sc[kt][r] * SCL + biasW[cur][bidx + kt * 16 + r];
    } else {
      const float cb = btabH[t * 64 - q0];
#pragma unroll
      for (int kt = 0; kt < 4; ++kt)
#pragma unroll
        for (int r = 0; r < 4; ++r)
          pp[kt][r] = sc[kt][r] * SCL + cb;
    }

    // ---- lane-local max (tree) ----
    float mx[8];
#pragma unroll
    for (int i = 0; i < 8; ++i)
      mx[i] = fmaxf(pp[i >> 1][(i & 1) * 2], pp[i >> 1][(i & 1) * 2 + 1]);
    float m01 = fmaxf(mx[0], mx[1]), m23 = fmaxf(mx[2], mx[3]);
    float m45 = fmaxf(mx[4], mx[5]), m67 = fmaxf(mx[6], mx[7]);
    float tm = fmaxf(fmaxf(m01, m23), fmaxf(m45, m67));

    // ---- lazy row-max ----
    if (!__all(tm <= mrun + THR)) {
      tm = fmaxf(tm, __shfl_xor(tm, 16));
      tm = fmaxf(tm, __shfl_xor(tm, 32));
      float mn = fmaxf(mrun, tm);
      float sfv = exp2_raw(mrun - mn);
      mrun = mn;
      lpart *= sfv;
#pragma unroll
      for (int r = 0; r < 4; ++r) {
        float sq = __shfl(sfv, (lane & 48) | (lg * 4 + r));
#pragma unroll
        for (int db = 0; db < 4; ++db) ov[db][r] *= sq;
      }
    }

    // ---- exp2 + per-lane partial sum ----
#pragma unroll
    for (int kt = 0; kt < 4; ++kt)
#pragma unroll
      for (int r = 0; r < 4; ++r)
        pp[kt][r] = exp2_raw(pp[kt][r] - mrun);
    float s8[8];
#pragma unroll
    for (int i = 0; i < 8; ++i)
      s8[i] = pp[i >> 1][(i & 1) * 2] + pp[i >> 1][(i & 1) * 2 + 1];
    float s01 = s8[0] + s8[1], s23 = s8[2] + s8[3];
    float s45 = s8[4] + s8[5], s67 = s8[6] + s8[7];
    lpart += (s01 + s23) + (s45 + s67);

    // ---- pack P via v_cvt_pk_bf16_f32 ----
    union { bf16x8 v; unsigned u[4]; } pk[2];
#pragma unroll
    for (int kh = 0; kh < 2; ++kh) {
      asm("v_cvt_pk_bf16_f32 %0, %1, %2"
          : "=v"(pk[kh].u[0]) : "v"(pp[2 * kh][0]), "v"(pp[2 * kh][1]));
      asm("v_cvt_pk_bf16_f32 %0, %1, %2"
          : "=v"(pk[kh].u[1]) : "v"(pp[2 * kh][2]), "v"(pp[2 * kh][3]));
      asm("v_cvt_pk_bf16_f32 %0, %1, %2"
          : "=v"(pk[kh].u[2]) : "v"(pp[2 * kh + 1][0]), "v"(pp[2 * kh + 1][1]));
      asm("v_cvt_pk_bf16_f32 %0, %1, %2"
          : "=v"(pk[kh].u[3]) : "v"(pp[2 * kh + 1][2]), "v"(pp[2 * kh + 1][3]));
    }

    // ---- PV ----
    __builtin_amdgcn_s_setprio(1);
#pragma unroll
    for (int kh = 0; kh < 2; ++kh)
#pragma unroll
      for (int db = 0; db < 4; ++db)
        ov[db] = __builtin_amdgcn_mfma_f32_16x16x32_bf16(
            pk[kh].v, vfr[kh][db], ov[db], 0, 0, 0);
    __builtin_amdgcn_s_setprio(0);
  }

  // ---- epilogue ----
  float lsum = lpart;
  lsum += __shfl_xor(lsum, 16);
  lsum += __shfl_xor(lsum, 32);
  float invl = 1.0f / lsum;
#pragma unroll
  for (int r = 0; r < 4; ++r) {
    float iv = __shfl(invl, (lane & 48) | (lg * 4 + r));
    size_t row = (size_t)(bb * S_ + qw + lg * 4 + r);
#pragma unroll
    for (int db = 0; db < 4; ++db)
      ctxb[row * 1024 + h * 64 + db * 16 + lr] = f2bf(ov[db][r] * iv);
  }
}

extern "C" void kernel_launch(void* const* d_in, const int* in_sizes, int n_in,
                              void* d_out, int out_size, void* d_ws, size_t ws_size,
                              hipStream_t stream) {
  const float* hs      = (const float*)d_in[0];
  const float* w_qkv   = (const float*)d_in[1];
  const float* b_qkv   = (const float*)d_in[2];
  const float* w_dense = (const float*)d_in[3];
  const float* b_dense = (const float*)d_in[4];
  const float* rtab    = (const float*)d_in[5];
  float* out = (float*)d_out;

  char* ws = (char*)d_ws;
  unsigned short* qkvb = (unsigned short*)ws;                          // 24 MB
  unsigned short* ctxb = (unsigned short*)(ws + (((size_t)24) << 20)); // 8 MB
  unsigned short* hsb  = (unsigned short*)(ws + (((size_t)32) << 20)); // 8 MB
  unsigned short* wqT  = (unsigned short*)(ws + (((size_t)40) << 20)); // 6 MB
  unsigned short* wdT  = (unsigned short*)(ws + (((size_t)46) << 20)); // 2 MB
  unsigned short* vP   = (unsigned short*)(ws + (((size_t)48) << 20)); // 8 MB
  float* biasTab       = (float*)(ws + (((size_t)56) << 20));          // 256 KB

  hipLaunchKernelGGL(prologue_kernel, dim3(3328), dim3(256), 0, stream,
                     hs, hsb, w_qkv, wqT, w_dense, wdT, rtab, biasTab);
  hipLaunchKernelGGL((gemm_mfma_kernel<true>), dim3(24, 32), dim3(256), 0, stream,
                     hsb, wqT, b_qkv, (void*)qkvb, 4096, 3072, 1024);
  hipLaunchKernelGGL(vperm_kernel, dim3(32, 16, 2), dim3(256), 0, stream,
                     qkvb, vP);
  hipLaunchKernelGGL(attn_mfma6_kernel, dim3(512), dim3(512), 0, stream,
                     qkvb, vP, biasTab, ctxb);
  hipLaunchKernelGGL((gemm_mfma64_kernel<false>), dim3(8, 64), dim3(256), 0, stream,
                     ctxb, wdT, b_dense, (void*)out, 4096, 1024, 1024);
}

// Round 15
// 127.214 us; speedup vs baseline: 1.2949x; 1.0141x over previous
//
#include <hip/hip_runtime.h>
#include <hip/hip_bf16.h>
#include <math.h>

#define S_ 2048

typedef __attribute__((ext_vector_type(8))) short bf16x8;
typedef __attribute__((ext_vector_type(4))) float f32x4;
typedef __attribute__((ext_vector_type(8))) unsigned short u16x8;
typedef __attribute__((ext_vector_type(4))) unsigned short u16x4;

__device__ inline unsigned short f2bf(float f) {
  union { float f; unsigned u; } x; x.f = f;
  unsigned r = x.u + 0x7fff + ((x.u >> 16) & 1);
  return (unsigned short)(r >> 16);
}

__device__ __forceinline__ float exp2_raw(float x) {
  float r;
  asm("v_exp_f32 %0, %1" : "=v"(r) : "v"(x));
  return r;
}

__device__ __forceinline__ void gll16(const unsigned short* g, unsigned short* l) {
  __builtin_amdgcn_global_load_lds(
      (const __attribute__((address_space(1))) unsigned int*)g,
      (__attribute__((address_space(3))) unsigned int*)l, 16, 0, 0);
}

// ---------------- fused prologue ----------------
__device__ __forceinline__ void transpose_tile(
    const float* __restrict__ in, unsigned short* __restrict__ out,
    int K, int N, int bx, int by, int tid, unsigned short (*tile)[72]) {
  const int k0 = by * 64, n0 = bx * 64;
  const int rr = tid >> 4, cc = (tid & 15) * 4;
#pragma unroll
  for (int p = 0; p < 4; ++p) {
    int k = rr + p * 16;
    float4 v = *(const float4*)&in[(size_t)(k0 + k) * N + n0 + cc];
    tile[k][cc + 0] = f2bf(v.x);
    tile[k][cc + 1] = f2bf(v.y);
    tile[k][cc + 2] = f2bf(v.z);
    tile[k][cc + 3] = f2bf(v.w);
  }
  __syncthreads();
#pragma unroll
  for (int p = 0; p < 4; ++p) {
    int n = rr + p * 16;
    u16x4 o;
    o[0] = tile[cc + 0][n];
    o[1] = tile[cc + 1][n];
    o[2] = tile[cc + 2][n];
    o[3] = tile[cc + 3][n];
    *(u16x4*)&out[(size_t)(n0 + n) * K + k0 + cc] = o;
  }
}

__global__ __launch_bounds__(256) void prologue_kernel(
    const float* __restrict__ hs, unsigned short* __restrict__ hsb,
    const float* __restrict__ w_qkv, unsigned short* __restrict__ wqT,
    const float* __restrict__ w_dense, unsigned short* __restrict__ wdT,
    const float* __restrict__ table, float* __restrict__ biasTab) {
  __shared__ unsigned short tile[64][72];
  const int blk = blockIdx.x;
  const int tid = threadIdx.x;
  if (blk < 2048) {
    int i = blk * 256 + tid;
    float4 a = ((const float4*)hs)[i * 2];
    float4 b = ((const float4*)hs)[i * 2 + 1];
    u16x8 o;
    o[0] = f2bf(a.x); o[1] = f2bf(a.y); o[2] = f2bf(a.z); o[3] = f2bf(a.w);
    o[4] = f2bf(b.x); o[5] = f2bf(b.y); o[6] = f2bf(b.z); o[7] = f2bf(b.w);
    *(u16x8*)&hsb[(size_t)i * 8] = o;
  } else if (blk < 2816) {
    int t = blk - 2048;
    transpose_tile(w_qkv, wqT, 1024, 3072, t % 48, t / 48, tid, tile);
  } else if (blk < 3072) {
    int t = blk - 2816;
    transpose_tile(w_dense, wdT, 1024, 1024, t % 16, t / 16, tid, tile);
  } else {
    int idx = (blk - 3072) * 256 + tid;
    int h = idx >> 12;
    int r = idx & 4095;
    int rel = r - 2047;
    int bucket = rel > 0 ? 16 : 0;
    int ar = rel < 0 ? -rel : rel;
    if (ar < 8) {
      bucket += ar;
    } else {
      float tmp = logf((float)ar / 8.0f);
      float lf = tmp / 2.7725887222397811f * 8.0f;
      int large = 8 + (int)lf;
      bucket += (large < 15 ? large : 15);
    }
    biasTab[idx] = table[h * 32 + bucket] * 1.44269504088896f;  // log2e domain
  }
}

// ------- bf16 MFMA GEMM, 128x128 tile, BK=64: C = A @ Bt^T + bias ------------
// XCD-swizzled. BF16OUT epilogue:
//   Q/K cols (n0 < 2048): per-wave LDS repack -> coalesced u16x8 qkvb stores.
//   V cols (n0 >= 2048): fused vperm — per-wave 64x64 transpose+kappa-permute
//   in LDS, write directly to vP[bb][h][d][k']; qkvb V region never written.
template <bool BF16OUT>
__global__ __launch_bounds__(256) void gemm_mfma_kernel(
    const unsigned short* __restrict__ A, const unsigned short* __restrict__ Bt,
    const float* __restrict__ bias, void* __restrict__ Cout,
    unsigned short* __restrict__ vP, int M, int N, int K) {
  __shared__ __align__(16) unsigned short As[128 * 64];
  __shared__ __align__(16) unsigned short Bs[128 * 64];
  const int tid = threadIdx.x;
  const int wave = tid >> 6, lane = tid & 63;
  const int lg = lane >> 4, lr = lane & 15;
  const int nbx = gridDim.x;
  const int flat = blockIdx.y * nbx + blockIdx.x;
  const int cpx = (nbx * gridDim.y) >> 3;
  const int swzid = (flat & 7) * cpx + (flat >> 3);
  const int m0 = (swzid / nbx) * 128, n0 = (swzid % nbx) * 128;
  const int wm = (wave & 1) * 64, wn = (wave >> 1) * 64;

  f32x4 acc[4][4] = {};

  const int rbase = tid >> 3;
  const int lsw = ((tid & 7) ^ (rbase & 7)) * 8;
  const unsigned short* aP[4];
  const unsigned short* bP[4];
  unsigned short* ldsA[4];
  unsigned short* ldsB[4];
#pragma unroll
  for (int g = 0; g < 4; ++g) {
    aP[g] = A + (size_t)(m0 + g * 32 + rbase) * K + lsw;
    bP[g] = Bt + (size_t)(n0 + g * 32 + rbase) * K + lsw;
    ldsA[g] = &As[g * 2048 + (tid & ~63) * 8];
    ldsB[g] = &Bs[g * 2048 + (tid & ~63) * 8];
  }

  for (int kt = 0; kt < K; kt += 64) {
    __syncthreads();
#pragma unroll
    for (int g = 0; g < 4; ++g) {
      gll16(aP[g] + kt, ldsA[g]);
      gll16(bP[g] + kt, ldsB[g]);
    }
    __syncthreads();
#pragma unroll
    for (int kh = 0; kh < 2; ++kh) {
      bf16x8 af[4], bfr[4];
#pragma unroll
      for (int t = 0; t < 4; ++t) {
        const int slot = ((kh * 4 + lg) ^ (lr & 7)) * 8;
        af[t]  = *(const bf16x8*)&As[(wm + t * 16 + lr) * 64 + slot];
        bfr[t] = *(const bf16x8*)&Bs[(wn + t * 16 + lr) * 64 + slot];
      }
#pragma unroll
      for (int i = 0; i < 4; ++i)
#pragma unroll
        for (int j = 0; j < 4; ++j)
          acc[i][j] = __builtin_amdgcn_mfma_f32_16x16x32_bf16(
              af[i], bfr[j], acc[i][j], 0, 0, 0);
    }
  }

  float bv[4];
#pragma unroll
  for (int j = 0; j < 4; ++j) bv[j] = bias[n0 + wn + j * 16 + lr];

  if constexpr (BF16OUT) {
    __syncthreads();   // all waves' frag reads of As/Bs complete before reuse
    if (n0 < 2048) {
      // ---- Q/K epilogue: repack -> coalesced qkvb stores ----
      unsigned short* rp = &As[wave * 1024];
#pragma unroll
      for (int i = 0; i < 4; ++i) {
#pragma unroll
        for (int j = 0; j < 4; ++j) {
          const int cw = ((j + lg) & 3) * 16 + lr;
#pragma unroll
          for (int r = 0; r < 4; ++r)
            rp[(lg * 4 + r) * 64 + cw] = f2bf(acc[i][j][r] + bv[j]);
        }
#pragma unroll
        for (int pass = 0; pass < 2; ++pass) {
          const int row = pass * 8 + (lane >> 3);
          const int cread = ((((lane & 7) >> 1) + (row >> 2)) & 3) * 16 +
                            (lane & 1) * 8;
          u16x8 v = *(const u16x8*)&rp[row * 64 + cread];
          *(u16x8*)&((unsigned short*)Cout)[
              (size_t)(m0 + wm + i * 16 + row) * N + n0 + wn + (lane & 7) * 8] = v;
        }
      }
    } else {
      // ---- V epilogue: fused vperm. Wave owns 64k x 64d subtile. ----
      // Store at R[d*64 + (ls^(d&7))*8 + e], ls=(i>>1)*4+lg, e=(i&1)*4+r
      // (exact inverse of attn's frag-read mapping; kappa matches P order).
      unsigned short* R = (wave < 2) ? &As[(wave & 1) * 4096]
                                     : &Bs[(wave & 1) * 4096];
#pragma unroll
      for (int i = 0; i < 4; ++i) {
        const int lsv = (i >> 1) * 4 + lg;
        const int ebase = (i & 1) * 4;
#pragma unroll
        for (int j = 0; j < 4; ++j) {
          const int d = j * 16 + lr;
          const int ps = lsv ^ (d & 7);
          u16x4 o;
#pragma unroll
          for (int r = 0; r < 4; ++r) o[r] = f2bf(acc[i][j][r] + bv[j]);
          *(u16x4*)&R[d * 64 + ps * 8 + ebase] = o;
        }
      }
      // read back (same wave; lgkm ordering) and store to vP
      const int krow0 = m0 + wm;
      const int bbv = krow0 >> 11;          // batch
      const int sbase = krow0 & 2047;       // seq base (64-aligned)
      const int h = ((n0 - 2048) >> 6) + (wave >> 1);
#pragma unroll
      for (int it = 0; it < 8; ++it) {
        const int d = it * 8 + (lane >> 3);
        const int c = lane & 7;
        u16x8 v = *(const u16x8*)&R[d * 64 + c * 8];
        *(u16x8*)&vP[((size_t)((bbv * 16 + h) * 64 + d)) * 2048 +
                     sbase + c * 8] = v;
      }
    }
  } else {
#pragma unroll
    for (int i = 0; i < 4; ++i)
#pragma unroll
      for (int j = 0; j < 4; ++j)
#pragma unroll
        for (int r = 0; r < 4; ++r) {
          int row = m0 + wm + i * 16 + lg * 4 + r;
          int col = n0 + wn + j * 16 + lr;
          ((float*)Cout)[(size_t)row * N + col] = acc[i][j][r] + bv[j];
        }
  }
}

// ------- bf16 MFMA GEMM, 64x128 tile, BK=64 (2x occupancy, small shapes) -----
template <bool BF16OUT>
__global__ __launch_bounds__(256) void gemm_mfma64_kernel(
    const unsigned short* __restrict__ A, const unsigned short* __restrict__ Bt,
    const float* __restrict__ bias, void* __restrict__ Cout,
    int M, int N, int K) {
  __shared__ __align__(16) unsigned short As[64 * 64];
  __shared__ __align__(16) unsigned short Bs[128 * 64];
  const int tid = threadIdx.x;
  const int wave = tid >> 6, lane = tid & 63;
  const int lg = lane >> 4, lr = lane & 15;
  const int nbx = gridDim.x;
  const int flat = blockIdx.y * nbx + blockIdx.x;
  const int cpx = (nbx * gridDim.y) >> 3;
  const int swzid = (flat & 7) * cpx + (flat >> 3);
  const int m0 = (swzid / nbx) * 64, n0 = (swzid % nbx) * 128;
  const int wm = (wave & 1) * 32, wn = (wave >> 1) * 64;

  f32x4 acc[2][4] = {};

  const int rbase = tid >> 3;
  const int lsw = ((tid & 7) ^ (rbase & 7)) * 8;
  const unsigned short* aP[2];
  const unsigned short* bP[4];
  unsigned short* ldsA[2];
  unsigned short* ldsB[4];
#pragma unroll
  for (int g = 0; g < 2; ++g) {
    aP[g] = A + (size_t)(m0 + g * 32 + rbase) * K + lsw;
    ldsA[g] = &As[g * 2048 + (tid & ~63) * 8];
  }
#pragma unroll
  for (int g = 0; g < 4; ++g) {
    bP[g] = Bt + (size_t)(n0 + g * 32 + rbase) * K + lsw;
    ldsB[g] = &Bs[g * 2048 + (tid & ~63) * 8];
  }

  for (int kt = 0; kt < K; kt += 64) {
    __syncthreads();
#pragma unroll
    for (int g = 0; g < 2; ++g) gll16(aP[g] + kt, ldsA[g]);
#pragma unroll
    for (int g = 0; g < 4; ++g) gll16(bP[g] + kt, ldsB[g]);
    __syncthreads();
#pragma unroll
    for (int kh = 0; kh < 2; ++kh) {
      bf16x8 af[2], bfr[4];
      const int slotb = ((kh * 4 + lg) ^ (lr & 7)) * 8;
#pragma unroll
      for (int t = 0; t < 2; ++t)
        af[t] = *(const bf16x8*)&As[(wm + t * 16 + lr) * 64 + slotb];
#pragma unroll
      for (int t = 0; t < 4; ++t)
        bfr[t] = *(const bf16x8*)&Bs[(wn + t * 16 + lr) * 64 + slotb];
#pragma unroll
      for (int i = 0; i < 2; ++i)
#pragma unroll
        for (int j = 0; j < 4; ++j)
          acc[i][j] = __builtin_amdgcn_mfma_f32_16x16x32_bf16(
              af[i], bfr[j], acc[i][j], 0, 0, 0);
    }
  }

  float bv[4];
#pragma unroll
  for (int j = 0; j < 4; ++j) bv[j] = bias[n0 + wn + j * 16 + lr];
#pragma unroll
  for (int i = 0; i < 2; ++i) {
#pragma unroll
    for (int j = 0; j < 4; ++j) {
#pragma unroll
      for (int r = 0; r < 4; ++r) {
        int row = m0 + wm + i * 16 + lg * 4 + r;
        int col = n0 + wn + j * 16 + lr;
        float val = acc[i][j][r] + bv[j];
        if constexpr (BF16OUT)
          ((unsigned short*)Cout)[(size_t)row * N + col] = f2bf(val);
        else
          ((float*)Cout)[(size_t)row * N + col] = val;
      }
    }
  }
}

// ---------------- bf16 MFMA flash attention v6 (+ V-frag hoist) ----------------
__global__ __launch_bounds__(512) void attn_mfma6_kernel(
    const unsigned short* __restrict__ qkvb, const unsigned short* __restrict__ vP,
    const float* __restrict__ biasTab, unsigned short* __restrict__ ctxb) {
  const int wg0 = blockIdx.x;
  const int wg = (wg0 & 7) * 64 + (wg0 >> 3);
  const int qt = wg & 15;
  const int h  = (wg >> 4) & 15;
  const int bb = wg >> 8;

  const int tid = threadIdx.x;
  const int wave = tid >> 6;
  const int lane = tid & 63;
  const int lg = lane >> 4;
  const int lr = lane & 15;

  __shared__ __align__(16) unsigned short Klds[2][4096];
  __shared__ __align__(16) unsigned short Vlds[2][4096];
  __shared__ float biasW[2][192];

  const int q0 = qt * 128;
  const int qw = q0 + wave * 16;
  const float SCL = 0.125f * 1.44269504088896f;
  const float THR = 11.5415603f;

  bf16x8 qf[2];
#pragma unroll
  for (int kh = 0; kh < 2; ++kh)
    qf[kh] = *(const bf16x8*)(qkvb +
        (size_t)(bb * S_ + qw + lr) * 3072 + h * 64 + kh * 32 + lg * 8);

  float mrun = -1e30f;
  float lpart = 0.f;
  f32x4 ov[4] = {};

  const int kk = tid >> 3, kpb = tid & 7;
  const unsigned short* kptr = qkvb + (size_t)(bb * S_ + kk) * 3072 + 1024 +
                               h * 64 + (kpb ^ (kk & 7)) * 8;
  const unsigned short* vptr = vP + ((size_t)((bb * 16 + h) * 64 + (tid >> 3))) * S_ +
                               (tid & 7) * 8;
  const float* btabH = biasTab + h * 4096 + 2047;

  auto nonuni = [&](int tt) {
    int rl = tt * 64 - q0;
    return !((rl - 127 >= 91) || (rl + 63 <= -91));
  };

  gll16(kptr, &Klds[0][(tid & ~63) * 8]);
  gll16(vptr, &Vlds[0][(tid & ~63) * 8]);
  if (nonuni(0) && tid < 192) biasW[0][tid] = btabH[-q0 - 127 + tid];

  for (int t = 0; t < 32; ++t) {
    const int cur = t & 1;
    __syncthreads();

    if (t < 31) {
      const size_t kadv = (size_t)(t + 1) * 64 * 3072;
      gll16(kptr + kadv, &Klds[cur ^ 1][(tid & ~63) * 8]);
      gll16(vptr + (t + 1) * 64, &Vlds[cur ^ 1][(tid & ~63) * 8]);
      if (nonuni(t + 1) && tid < 192)
        biasW[cur ^ 1][tid] = btabH[(t + 1) * 64 - q0 - 127 + tid];
    }

    // ---- QK^T swapped ----
    f32x4 sc[4] = {};
    __builtin_amdgcn_s_setprio(1);
#pragma unroll
    for (int kt = 0; kt < 4; ++kt) {
      const unsigned short* kr = &Klds[cur][(kt * 16 + lr) * 64];
      bf16x8 kf0 = *(const bf16x8*)(kr + ((lg)     ^ (lr & 7)) * 8);
      bf16x8 kf1 = *(const bf16x8*)(kr + ((4 + lg) ^ (lr & 7)) * 8);
      sc[kt] = __builtin_amdgcn_mfma_f32_16x16x32_bf16(kf0, qf[0], sc[kt], 0, 0, 0);
      sc[kt] = __builtin_amdgcn_mfma_f32_16x16x32_bf16(kf1, qf[1], sc[kt], 0, 0, 0);
    }
    __builtin_amdgcn_s_setprio(0);

    // ---- V fragments hoisted ----
    bf16x8 vfr[2][4];
#pragma unroll
    for (int kh = 0; kh < 2; ++kh)
#pragma unroll
      for (int db = 0; db < 4; ++db)
        vfr[kh][db] = *(const bf16x8*)&Vlds[cur][
            (db * 16 + lr) * 64 + ((4 * kh + lg) ^ (lr & 7)) * 8];

    // ---- bias (log2e domain) ----
    float pp[4][4];
    if (nonuni(t)) {
      const int bidx = 127 + lg * 4 - wave * 16 - lr;
#pragma unroll
      for (int kt = 0; kt < 4; ++kt)
#pragma unroll
        for (int r = 0; r < 4; ++r)
          pp[kt][r] = sc[kt][r] * SCL + biasW[cur][bidx + kt * 16 + r];
    } else {
      const float cb = btabH[t * 64 - q0];
#pragma unroll
      for (int kt = 0; kt < 4; ++kt)
#pragma unroll
        for (int r = 0; r < 4; ++r)
          pp[kt][r] = sc[kt][r] * SCL + cb;
    }

    // ---- lane-local max (tree) ----
    float mx[8];
#pragma unroll
    for (int i = 0; i < 8; ++i)
      mx[i] = fmaxf(pp[i >> 1][(i & 1) * 2], pp[i >> 1][(i & 1) * 2 + 1]);
    float m01 = fmaxf(mx[0], mx[1]), m23 = fmaxf(mx[2], mx[3]);
    float m45 = fmaxf(mx[4], mx[5]), m67 = fmaxf(mx[6], mx[7]);
    float tm = fmaxf(fmaxf(m01, m23), fmaxf(m45, m67));

    // ---- lazy row-max ----
    if (!__all(tm <= mrun + THR)) {
      tm = fmaxf(tm, __shfl_xor(tm, 16));
      tm = fmaxf(tm, __shfl_xor(tm, 32));
      float mn = fmaxf(mrun, tm);
      float sfv = exp2_raw(mrun - mn);
      mrun = mn;
      lpart *= sfv;
#pragma unroll
      for (int r = 0; r < 4; ++r) {
        float sq = __shfl(sfv, (lane & 48) | (lg * 4 + r));
#pragma unroll
        for (int db = 0; db < 4; ++db) ov[db][r] *= sq;
      }
    }

    // ---- exp2 + per-lane partial sum ----
#pragma unroll
    for (int kt = 0; kt < 4; ++kt)
#pragma unroll
      for (int r = 0; r < 4; ++r)
        pp[kt][r] = exp2_raw(pp[kt][r] - mrun);
    float s8[8];
#pragma unroll
    for (int i = 0; i < 8; ++i)
      s8[i] = pp[i >> 1][(i & 1) * 2] + pp[i >> 1][(i & 1) * 2 + 1];
    float s01 = s8[0] + s8[1], s23 = s8[2] + s8[3];
    float s45 = s8[4] + s8[5], s67 = s8[6] + s8[7];
    lpart += (s01 + s23) + (s45 + s67);

    // ---- pack P via v_cvt_pk_bf16_f32 ----
    union { bf16x8 v; unsigned u[4]; } pk[2];
#pragma unroll
    for (int kh = 0; kh < 2; ++kh) {
      asm("v_cvt_pk_bf16_f32 %0, %1, %2"
          : "=v"(pk[kh].u[0]) : "v"(pp[2 * kh][0]), "v"(pp[2 * kh][1]));
      asm("v_cvt_pk_bf16_f32 %0, %1, %2"
          : "=v"(pk[kh].u[1]) : "v"(pp[2 * kh][2]), "v"(pp[2 * kh][3]));
      asm("v_cvt_pk_bf16_f32 %0, %1, %2"
          : "=v"(pk[kh].u[2]) : "v"(pp[2 * kh + 1][0]), "v"(pp[2 * kh + 1][1]));
      asm("v_cvt_pk_bf16_f32 %0, %1, %2"
          : "=v"(pk[kh].u[3]) : "v"(pp[2 * kh + 1][2]), "v"(pp[2 * kh + 1][3]));
    }

    // ---- PV ----
    __builtin_amdgcn_s_setprio(1);
#pragma unroll
    for (int kh = 0; kh < 2; ++kh)
#pragma unroll
      for (int db = 0; db < 4; ++db)
        ov[db] = __builtin_amdgcn_mfma_f32_16x16x32_bf16(
            pk[kh].v, vfr[kh][db], ov[db], 0, 0, 0);
    __builtin_amdgcn_s_setprio(0);
  }

  // ---- epilogue ----
  float lsum = lpart;
  lsum += __shfl_xor(lsum, 16);
  lsum += __shfl_xor(lsum, 32);
  float invl = 1.0f / lsum;
#pragma unroll
  for (int r = 0; r < 4; ++r) {
    float iv = __shfl(invl, (lane & 48) | (lg * 4 + r));
    size_t row = (size_t)(bb * S_ + qw + lg * 4 + r);
#pragma unroll
    for (int db = 0; db < 4; ++db)
      ctxb[row * 1024 + h * 64 + db * 16 + lr] = f2bf(ov[db][r] * iv);
  }
}

extern "C" void kernel_launch(void* const* d_in, const int* in_sizes, int n_in,
                              void* d_out, int out_size, void* d_ws, size_t ws_size,
                              hipStream_t stream) {
  const float* hs      = (const float*)d_in[0];
  const float* w_qkv   = (const float*)d_in[1];
  const float* b_qkv   = (const float*)d_in[2];
  const float* w_dense = (const float*)d_in[3];
  const float* b_dense = (const float*)d_in[4];
  const float* rtab    = (const float*)d_in[5];
  float* out = (float*)d_out;

  char* ws = (char*)d_ws;
  unsigned short* qkvb = (unsigned short*)ws;                          // 24 MB
  unsigned short* ctxb = (unsigned short*)(ws + (((size_t)24) << 20)); // 8 MB
  unsigned short* hsb  = (unsigned short*)(ws + (((size_t)32) << 20)); // 8 MB
  unsigned short* wqT  = (unsigned short*)(ws + (((size_t)40) << 20)); // 6 MB
  unsigned short* wdT  = (unsigned short*)(ws + (((size_t)46) << 20)); // 2 MB
  unsigned short* vP   = (unsigned short*)(ws + (((size_t)48) << 20)); // 8 MB
  float* biasTab       = (float*)(ws + (((size_t)56) << 20));          // 256 KB

  hipLaunchKernelGGL(prologue_kernel, dim3(3328), dim3(256), 0, stream,
                     hs, hsb, w_qkv, wqT, w_dense, wdT, rtab, biasTab);
  hipLaunchKernelGGL((gemm_mfma_kernel<true>), dim3(24, 32), dim3(256), 0, stream,
                     hsb, wqT, b_qkv, (void*)qkvb, vP, 4096, 3072, 1024);
  hipLaunchKernelGGL(attn_mfma6_kernel, dim3(512), dim3(512), 0, stream,
                     qkvb, vP, biasTab, ctxb);
  hipLaunchKernelGGL((gemm_mfma64_kernel<false>), dim3(8, 64), dim3(256), 0, stream,
                     ctxb, wdT, b_dense, (void*)out, 4096, 1024, 1024);
}